// Round 10
// baseline (279.362 us; speedup 1.0000x reference)
//
#include <hip/hip_runtime.h>
#include <hip/hip_bf16.h>

#define INF_F (__builtin_inff())

typedef __attribute__((ext_vector_type(8))) short bf16x8;
typedef __attribute__((ext_vector_type(4))) float f32x4;

__device__ __forceinline__ unsigned short f2bf(float f) {
  __hip_bfloat16 h = __float2bfloat16(f);
  return __builtin_bit_cast(unsigned short, h);
}
__device__ __forceinline__ float bf2f(unsigned short u) {
  return __uint_as_float((unsigned)u << 16);
}

// branchy sorted top-3 insert (macro, scalar state) - used on cold paths only
#define TOP3_INS(d, sj, E0, E1, E2, J0, J1, J2)                      \
  {                                                                  \
    bool l0 = (d) < E0, l1 = (d) < E1;                               \
    E2 = l1 ? E1 : (d); J2 = l1 ? J1 : (sj);                         \
    E1 = l0 ? E0 : (l1 ? (d) : E1); J1 = l0 ? J0 : (l1 ? (sj) : J1); \
    E0 = l0 ? (d) : E0; J0 = l0 ? (sj) : J0;                         \
  }

// branchless hot-path insert: values via min/med3 (3 ops), indices via
// 3 cmp + 5 cndmask. R9 lesson: the "rare" insert branch is per-WAVE and
// with 256 query-states/wave it is ~always taken -> unconditional is cheaper.
// Strict < + ascending s preserves top_k's lowest-index tie order.
#define TOP3_INS_BL(d, sj, E0, E1, E2, J0, J1, J2)                   \
  {                                                                  \
    bool l0 = (d) < E0, l1 = (d) < E1, l2 = (d) < E2;                \
    float ne2 = __builtin_amdgcn_fmed3f(E1, (d), E2);                \
    float ne1 = __builtin_amdgcn_fmed3f(E0, (d), E1);                \
    float ne0 = fminf((d), E0);                                      \
    J2 = l1 ? J1 : (l2 ? (sj) : J2);                                 \
    J1 = l0 ? J0 : (l1 ? (sj) : J1);                                 \
    J0 = l0 ? (sj) : J0;                                             \
    E2 = ne2; E1 = ne1; E0 = ne0;                                    \
  }

// ---------------------------------------------------------------------------
// B=4, N=16384, S=4096, D1=128, D2=256, MLP=(256,128). M = B*N = 65536.
// X: [65536][384] bf16 (cols 0..127 = points1^T, 128..383 = interp)
// h1T: [65536][256] bf16 ; out2T: [65536][128] fp32.
// GEMMs: D[c][n] = W[c][k] * X[n][k] via mfma_f32_16x16x32_bf16.
// ---------------------------------------------------------------------------

// points2 [B][256][4096] fp32 -> p2t [B][4096][256] bf16 (coalesced gather rows)
__global__ __launch_bounds__(256) void transpose_k(const float* __restrict__ in,
                                                   unsigned short* __restrict__ out) {
  __shared__ float tile[32][33];
  int b = blockIdx.z;
  int s0 = blockIdx.x * 32;
  int k0 = blockIdx.y * 32;
  int tx = threadIdx.x, ty = threadIdx.y;  // 32 x 8
  const float* src = in + ((size_t)b * 256 + k0) * 4096 + s0;
  for (int r = ty; r < 32; r += 8) tile[r][tx] = src[(size_t)r * 4096 + tx];
  __syncthreads();
  unsigned short* dst = out + ((size_t)b * 4096 + s0) * 256 + k0;
  for (int r = ty; r < 32; r += 8) dst[(size_t)r * 256 + tx] = f2bf(tile[tx][r]);
}

// p1 [B][128][16384] fp32 -> X[b*16384+n][0..127] bf16 (transposed)
__global__ __launch_bounds__(256) void p1t_k(const float* __restrict__ p1,
                                             unsigned short* __restrict__ X) {
  __shared__ float tile[32][33];
  int b = blockIdx.z;
  int n0 = blockIdx.x * 32;
  int c0 = blockIdx.y * 32;
  int tx = threadIdx.x, ty = threadIdx.y;
  const float* src = p1 + ((size_t)b * 128 + c0) * 16384 + n0;
  for (int r = ty; r < 32; r += 8) tile[r][tx] = src[(size_t)r * 16384 + tx];
  __syncthreads();
  for (int r = ty; r < 32; r += 8)
    X[((size_t)(b * 16384 + n0 + r)) * 384 + c0 + tx] = f2bf(tile[tx][r]);
}

// w1 [256][384], w2 [128][256] fp32 -> bf16 copies (same layout)
__global__ __launch_bounds__(256) void wcvt_k(const float* __restrict__ w1,
                                              const float* __restrict__ w2,
                                              unsigned short* __restrict__ w1b,
                                              unsigned short* __restrict__ w2b) {
  int id = blockIdx.x * 256 + threadIdx.x;
  if (id < 98304) w1b[id] = f2bf(w1[id]);
  else w2b[id - 98304] = f2bf(w2[id - 98304]);
}

// 3-NN stage 1. 1024 blocks = 64 query-chunks (1024 q) x 16 S-slices (256
// src, 4KB LDS). 256 thr x 4 queries/thread: one broadcast ds_read_b128
// feeds 256 pairs. Hot loop: 4-op distance (precomputed -2p per query) +
// 11-op branchless med3 insert, unconditional (R9: wave-level branch was
// ~always taken). Validity folded into staged |p|^2 (3e38 if batch-id !=
// common -> d>BIG -> weight 0). Per-query exact inline fallback if its id
// != common (never taken on this data). All state named scalars (R8 lesson).
__global__ __launch_bounds__(256) void knn_k(const float* __restrict__ xyz1,
                                             const float* __restrict__ xyz2,
                                             const int* __restrict__ idx1,
                                             const int* __restrict__ idx2,
                                             float* __restrict__ rec) {
  __shared__ float4 sP[256];  // 4KB
  int bid = blockIdx.x;
  int chunk = bid >> 4, sl = bid & 15;
  int b = chunk >> 4;            // 16 chunks per batch (1024 queries each)
  int nloc = (chunk & 15) << 10; // query base within batch
  int t = threadIdx.x;
  int common = idx1[b * 16384 + nloc];
  int sbase = sl << 8;
  {
    int gs = sbase + t;
    float x = xyz2[(b * 3 + 0) * 4096 + gs];
    float y = xyz2[(b * 3 + 1) * 4096 + gs];
    float z = xyz2[(b * 3 + 2) * 4096 + gs];
    float w = fmaf(x, x, fmaf(y, y, z * z));
    int sid = idx2[b * 4096 + gs];
    w = (sid == common) ? w : 3e38f;
    sP[t] = make_float4(x, y, z, w);
  }
  __syncthreads();
  int q0i = b * 16384 + nloc + t;  // queries: q0i, +256, +512, +768
  float px0 = xyz1[(b * 3 + 0) * 16384 + nloc + t];
  float py0 = xyz1[(b * 3 + 1) * 16384 + nloc + t];
  float pz0 = xyz1[(b * 3 + 2) * 16384 + nloc + t];
  float px1 = xyz1[(b * 3 + 0) * 16384 + nloc + t + 256];
  float py1 = xyz1[(b * 3 + 1) * 16384 + nloc + t + 256];
  float pz1 = xyz1[(b * 3 + 2) * 16384 + nloc + t + 256];
  float px2 = xyz1[(b * 3 + 0) * 16384 + nloc + t + 512];
  float py2 = xyz1[(b * 3 + 1) * 16384 + nloc + t + 512];
  float pz2 = xyz1[(b * 3 + 2) * 16384 + nloc + t + 512];
  float px3 = xyz1[(b * 3 + 0) * 16384 + nloc + t + 768];
  float py3 = xyz1[(b * 3 + 1) * 16384 + nloc + t + 768];
  float pz3 = xyz1[(b * 3 + 2) * 16384 + nloc + t + 768];
  int id0 = idx1[q0i], id1 = idx1[q0i + 256], id2 = idx1[q0i + 512], id3 = idx1[q0i + 768];
  float pn0 = fmaf(px0, px0, fmaf(py0, py0, pz0 * pz0));
  float pn1 = fmaf(px1, px1, fmaf(py1, py1, pz1 * pz1));
  float pn2 = fmaf(px2, px2, fmaf(py2, py2, pz2 * pz2));
  float pn3 = fmaf(px3, px3, fmaf(py3, py3, pz3 * pz3));
  // hot-loop distance form: d = ((qz*z + pn) fma qy*y fma qx*x) + w
  // with q = -2*p. Same value as fmaf(-2,dot,pn+w) up to fp assoc of the
  // final add; ranking uses the same d for all candidates of a query.
  float qx0 = -2.f * px0, qy0 = -2.f * py0, qz0 = -2.f * pz0;
  float qx1 = -2.f * px1, qy1 = -2.f * py1, qz1 = -2.f * pz1;
  float qx2 = -2.f * px2, qy2 = -2.f * py2, qz2 = -2.f * pz2;
  float qx3 = -2.f * px3, qy3 = -2.f * py3, qz3 = -2.f * pz3;
  float e00 = INF_F, e10 = INF_F, e20 = INF_F;
  float e01 = INF_F, e11 = INF_F, e21 = INF_F;
  float e02 = INF_F, e12 = INF_F, e22 = INF_F;
  float e03 = INF_F, e13 = INF_F, e23 = INF_F;
  int j00 = 0, j10 = 0, j20 = 0;
  int j01 = 0, j11 = 0, j21 = 0;
  int j02 = 0, j12 = 0, j22 = 0;
  int j03 = 0, j13 = 0, j23 = 0;
#pragma unroll 4
  for (int s = 0; s < 256; ++s) {
    float4 p = sP[s];  // wave-uniform addr -> LDS broadcast, conflict-free
    int sj = sbase + s;
    float d0 = fmaf(qx0, p.x, fmaf(qy0, p.y, fmaf(qz0, p.z, pn0))) + p.w;
    float d1 = fmaf(qx1, p.x, fmaf(qy1, p.y, fmaf(qz1, p.z, pn1))) + p.w;
    float d2 = fmaf(qx2, p.x, fmaf(qy2, p.y, fmaf(qz2, p.z, pn2))) + p.w;
    float d3 = fmaf(qx3, p.x, fmaf(qy3, p.y, fmaf(qz3, p.z, pn3))) + p.w;
    TOP3_INS_BL(d0, sj, e00, e10, e20, j00, j10, j20);
    TOP3_INS_BL(d1, sj, e01, e11, e21, j01, j11, j21);
    TOP3_INS_BL(d2, sj, e02, e12, e22, j02, j12, j22);
    TOP3_INS_BL(d3, sj, e03, e13, e23, j03, j13, j23);
  }
  // exact inline fallback per query when its id != common (never on this data)
#define KNN_FB(MYID, PX, PY, PZ, PN, E0, E1, E2, J0, J1, J2)              \
  if (__builtin_expect((MYID) != common, 0)) {                            \
    E0 = INF_F; E1 = INF_F; E2 = INF_F; J0 = 0; J1 = 0; J2 = 0;           \
    for (int s = 0; s < 256; ++s) {                                       \
      int gs = sbase + s;                                                 \
      float x = xyz2[(b * 3 + 0) * 4096 + gs];                            \
      float y = xyz2[(b * 3 + 1) * 4096 + gs];                            \
      float z = xyz2[(b * 3 + 2) * 4096 + gs];                            \
      float w = fmaf(x, x, fmaf(y, y, z * z));                            \
      float d = fmaf(PX * -2.f, x, fmaf(PY * -2.f, y,                     \
                     fmaf((PZ) * -2.f, z, PN))) + w;                      \
      d = (idx2[b * 4096 + gs] == (MYID)) ? d : INF_F;                    \
      if (d < E2) TOP3_INS(d, gs, E0, E1, E2, J0, J1, J2);                \
    }                                                                     \
  }
  KNN_FB(id0, px0, py0, pz0, pn0, e00, e10, e20, j00, j10, j20);
  KNN_FB(id1, px1, py1, pz1, pn1, e01, e11, e21, j01, j11, j21);
  KNN_FB(id2, px2, py2, pz2, pn2, e02, e12, e22, j02, j12, j22);
  KNN_FB(id3, px3, py3, pz3, pn3, e03, e13, e23, j03, j13, j23);
#undef KNN_FB
  // rec layout [slice][query]: lane-consecutive 24B records => coalesced
  {
    float* r = &rec[((size_t)sl * 65536 + q0i) * 6];
    r[0] = e00; r[1] = e10; r[2] = e20;
    ((int*)r)[3] = j00; ((int*)r)[4] = j10; ((int*)r)[5] = j20;
    r = &rec[((size_t)sl * 65536 + q0i + 256) * 6];
    r[0] = e01; r[1] = e11; r[2] = e21;
    ((int*)r)[3] = j01; ((int*)r)[4] = j11; ((int*)r)[5] = j21;
    r = &rec[((size_t)sl * 65536 + q0i + 512) * 6];
    r[0] = e02; r[1] = e12; r[2] = e22;
    ((int*)r)[3] = j02; ((int*)r)[4] = j12; ((int*)r)[5] = j22;
    r = &rec[((size_t)sl * 65536 + q0i + 768) * 6];
    r[0] = e03; r[1] = e13; r[2] = e23;
    ((int*)r)[3] = j03; ((int*)r)[4] = j13; ((int*)r)[5] = j23;
  }
}

// 3-NN stage 2: merge 16 S-slice records (ascending slice order, lex (d,idx)
// = exact top_k tie semantics), compute inverse-distance weights.
__global__ __launch_bounds__(256) void knnmerge_k(const float* __restrict__ rec,
                                                  int* __restrict__ idx3,
                                                  float* __restrict__ wgt) {
  int i = blockIdx.x * 256 + threadIdx.x;  // 65536 queries
  float e0, e1, e2;
  int j0, j1, j2;
  {
    const float* r = &rec[(size_t)i * 6];
    e0 = r[0]; e1 = r[1]; e2 = r[2];
    j0 = ((const int*)r)[3]; j1 = ((const int*)r)[4]; j2 = ((const int*)r)[5];
  }
  for (int c = 1; c < 16; ++c) {
    const float* r = &rec[((size_t)c * 65536 + i) * 6];
    const int* ir = (const int*)r;
#pragma unroll
    for (int w = 0; w < 3; ++w) {
      float d = r[w];
      int sj = ir[3 + w];
      bool l0 = (d < e0) || (d == e0 && sj < j0);
      bool l1 = (d < e1) || (d == e1 && sj < j1);
      bool l2 = (d < e2) || (d == e2 && sj < j2);
      e2 = l1 ? e1 : (l2 ? d : e2);
      j2 = l1 ? j1 : (l2 ? sj : j2);
      e1 = l0 ? e0 : (l1 ? d : e1);
      j1 = l0 ? j0 : (l1 ? sj : j1);
      e0 = l0 ? d : e0;
      j0 = l0 ? sj : j0;
    }
  }
  float r0 = 1.f / (e0 + 1e-8f);
  float r1 = 1.f / (e1 + 1e-8f);
  float r2 = 1.f / (e2 + 1e-8f);
  float rs = r0 + r1 + r2;
  float w0 = (e0 > 1e8f) ? 0.f : r0 / rs;  // ref: where(d3>BIG,0)+nan_to_num
  float w1 = (e1 > 1e8f) ? 0.f : r1 / rs;
  float w2 = (e2 > 1e8f) ? 0.f : r2 / rs;
  idx3[(size_t)i * 3 + 0] = j0; idx3[(size_t)i * 3 + 1] = j1; idx3[(size_t)i * 3 + 2] = j2;
  wgt[(size_t)i * 3 + 0] = w0;  wgt[(size_t)i * 3 + 1] = w1;  wgt[(size_t)i * 3 + 2] = w2;
}

// interp (bf16 p2t rows) -> X[i][128+k] bf16
__global__ __launch_bounds__(256) void interp_k(const unsigned short* __restrict__ p2t,
                                                const int* __restrict__ idx3,
                                                const float* __restrict__ wgt,
                                                unsigned short* __restrict__ X) {
  int i0 = blockIdx.x * 128;
  int b = i0 >> 14;
  int k = threadIdx.x;
  const unsigned short* base = p2t + (size_t)b * 4096 * 256;
#pragma unroll 2
  for (int ii = 0; ii < 128; ++ii) {
    int i = i0 + ii;
    int id0 = idx3[i * 3 + 0], id1 = idx3[i * 3 + 1], id2 = idx3[i * 3 + 2];
    float w0 = wgt[i * 3 + 0], w1v = wgt[i * 3 + 1], w2v = wgt[i * 3 + 2];
    float v = w0 * bf2f(base[id0 * 256 + k]);
    v = fmaf(w1v, bf2f(base[id1 * 256 + k]), v);
    v = fmaf(w2v, bf2f(base[id2 * 256 + k]), v);
    X[(size_t)i * 384 + 128 + k] = f2bf(v);
  }
}

// GEMM1 (MFMA): h1T[n][c] = sum_k w1[c][k] X[n][k]. 128x128 tile, BK=32,
// K=384. grid (512, 2).
__global__ __launch_bounds__(256) void gemm1_k(const unsigned short* __restrict__ X,
                                               const unsigned short* __restrict__ Wb,
                                               unsigned short* __restrict__ h1T) {
  __shared__ unsigned short sW[128][40];
  __shared__ unsigned short sX[128][40];
  int t = threadIdx.x;
  int i0 = blockIdx.x * 128;
  int c0 = blockIdx.y * 128;
  int w = t >> 6, lane = t & 63;
  int wc = (w & 1) * 64, wn = (w >> 1) * 64;
  int l15 = lane & 15, g = lane >> 4;
  f32x4 acc[4][4];
#pragma unroll
  for (int a = 0; a < 4; ++a)
#pragma unroll
    for (int bq = 0; bq < 4; ++bq) acc[a][bq] = (f32x4)0.f;
  int sr = t & 127, sh = t >> 7;
  for (int kc = 0; kc < 12; ++kc) {
    int k0 = kc * 32;
    __syncthreads();
    {
      const uint4* gw = (const uint4*)&Wb[(size_t)(c0 + sr) * 384 + k0 + sh * 16];
      uint4 v0 = gw[0], v1 = gw[1];
      *(uint4*)&sW[sr][sh * 16] = v0;
      *(uint4*)&sW[sr][sh * 16 + 8] = v1;
      const uint4* gx = (const uint4*)&X[(size_t)(i0 + sr) * 384 + k0 + sh * 16];
      uint4 x0 = gx[0], x1 = gx[1];
      *(uint4*)&sX[sr][sh * 16] = x0;
      *(uint4*)&sX[sr][sh * 16 + 8] = x1;
    }
    __syncthreads();
    bf16x8 a[4], b[4];
#pragma unroll
    for (int tm = 0; tm < 4; ++tm)
      a[tm] = *(const bf16x8*)&sW[wc + tm * 16 + l15][g * 8];
#pragma unroll
    for (int tn = 0; tn < 4; ++tn)
      b[tn] = *(const bf16x8*)&sX[wn + tn * 16 + l15][g * 8];
#pragma unroll
    for (int tm = 0; tm < 4; ++tm)
#pragma unroll
      for (int tn = 0; tn < 4; ++tn)
        acc[tm][tn] = __builtin_amdgcn_mfma_f32_16x16x32_bf16(a[tm], b[tn], acc[tm][tn], 0, 0, 0);
  }
#pragma unroll
  for (int tm = 0; tm < 4; ++tm)
#pragma unroll
    for (int tn = 0; tn < 4; ++tn) {
      int c = c0 + wc + tm * 16 + g * 4;
      int n = i0 + wn + tn * 16 + l15;
      f32x4 v = acc[tm][tn];
      ushort4 o;
      o.x = f2bf(v[0]); o.y = f2bf(v[1]); o.z = f2bf(v[2]); o.w = f2bf(v[3]);
      *(ushort4*)&h1T[(size_t)n * 256 + c] = o;
    }
}

// BN1 stats over h1T bf16 [65536][256]
__global__ __launch_bounds__(256) void bnstats1_k(const unsigned short* __restrict__ h,
                                                  float* __restrict__ part) {
  int t = threadIdx.x, q = t & 63, ro = t >> 6;
  int r0 = blockIdx.x * 256;
  float s0 = 0, s1 = 0, s2 = 0, s3 = 0, q0 = 0, q1 = 0, q2 = 0, q3 = 0;
  for (int it = 0; it < 64; ++it) {
    size_t r = r0 + it * 4 + ro;
    ushort4 v = *(const ushort4*)&h[r * 256 + q * 4];
    float f0 = bf2f(v.x), f1 = bf2f(v.y), f2 = bf2f(v.z), f3 = bf2f(v.w);
    s0 += f0; q0 += f0 * f0;
    s1 += f1; q1 += f1 * f1;
    s2 += f2; q2 += f2 * f2;
    s3 += f3; q3 += f3 * f3;
  }
  __shared__ float sm[256][8];
  sm[t][0] = s0; sm[t][1] = s1; sm[t][2] = s2; sm[t][3] = s3;
  sm[t][4] = q0; sm[t][5] = q1; sm[t][6] = q2; sm[t][7] = q3;
  __syncthreads();
  if (t < 64) {
#pragma unroll
    for (int j = 1; j < 4; ++j)
#pragma unroll
      for (int e = 0; e < 8; ++e) sm[t][e] += sm[t + 64 * j][e];
#pragma unroll
    for (int i = 0; i < 4; ++i) {
      part[((size_t)blockIdx.x * 256 + t * 4 + i) * 2 + 0] = sm[t][i];
      part[((size_t)blockIdx.x * 256 + t * 4 + i) * 2 + 1] = sm[t][4 + i];
    }
  }
}

// BN2 stats over out2T fp32 [65536][128]
__global__ __launch_bounds__(256) void bnstats2_k(const float* __restrict__ o2,
                                                  float* __restrict__ part) {
  int t = threadIdx.x, q = t & 31, ro = t >> 5;
  int r0 = blockIdx.x * 256;
  float s0 = 0, s1 = 0, s2 = 0, s3 = 0, q0 = 0, q1 = 0, q2 = 0, q3 = 0;
  for (int it = 0; it < 32; ++it) {
    size_t r = r0 + it * 8 + ro;
    float4 v = *(const float4*)&o2[r * 128 + q * 4];
    s0 += v.x; q0 += v.x * v.x;
    s1 += v.y; q1 += v.y * v.y;
    s2 += v.z; q2 += v.z * v.z;
    s3 += v.w; q3 += v.w * v.w;
  }
  __shared__ float sm[256][8];
  sm[t][0] = s0; sm[t][1] = s1; sm[t][2] = s2; sm[t][3] = s3;
  sm[t][4] = q0; sm[t][5] = q1; sm[t][6] = q2; sm[t][7] = q3;
  __syncthreads();
  if (t < 32) {
#pragma unroll
    for (int j = 1; j < 8; ++j)
#pragma unroll
      for (int e = 0; e < 8; ++e) sm[t][e] += sm[t + 32 * j][e];
#pragma unroll
    for (int i = 0; i < 4; ++i) {
      part[((size_t)blockIdx.x * 128 + t * 4 + i) * 2 + 0] = sm[t][i];
      part[((size_t)blockIdx.x * 128 + t * 4 + i) * 2 + 1] = sm[t][4 + i];
    }
  }
}

// fold partials -> per-channel a*x + c
template <int C>
__global__ __launch_bounds__(256) void bnfold_k(const float* __restrict__ part,
                                                const float* __restrict__ g,
                                                const float* __restrict__ be,
                                                float* __restrict__ A,
                                                float* __restrict__ Cc) {
  int c = threadIdx.x;
  if (c >= C) return;
  float s1 = 0.f, s2 = 0.f;
  for (int b = 0; b < 256; ++b) {
    s1 += part[((size_t)b * C + c) * 2 + 0];
    s2 += part[((size_t)b * C + c) * 2 + 1];
  }
  float mean = s1 * (1.f / 65536.f);
  float var = s2 * (1.f / 65536.f) - mean * mean;  // biased, as torch BN
  float a = g[c] * rsqrtf(var + 1e-5f);
  A[c] = a;
  Cc[c] = be[c] - mean * a;
}

// GEMM2 (MFMA) with fused BN1+ReLU on staging: out2T[n][c2] =
// sum_k w2[c2][k] relu(a1[k]*h1T[n][k]+c1[k]). K=256. grid (512).
__global__ __launch_bounds__(256) void gemm2_k(const unsigned short* __restrict__ h1T,
                                               const unsigned short* __restrict__ Wb,
                                               const float* __restrict__ A,
                                               const float* __restrict__ C,
                                               float* __restrict__ o2) {
  __shared__ unsigned short sW[128][40];
  __shared__ unsigned short sX[128][40];
  int t = threadIdx.x;
  int i0 = blockIdx.x * 128;
  int w = t >> 6, lane = t & 63;
  int wc = (w & 1) * 64, wn = (w >> 1) * 64;
  int l15 = lane & 15, g = lane >> 4;
  f32x4 acc[4][4];
#pragma unroll
  for (int a = 0; a < 4; ++a)
#pragma unroll
    for (int bq = 0; bq < 4; ++bq) acc[a][bq] = (f32x4)0.f;
  int sr = t & 127, sh = t >> 7;
  for (int kc = 0; kc < 8; ++kc) {
    int k0 = kc * 32;
    int kcol = k0 + sh * 16;
    __syncthreads();
    {
      const uint4* gw = (const uint4*)&Wb[(size_t)sr * 256 + kcol];
      uint4 v0 = gw[0], v1 = gw[1];
      *(uint4*)&sW[sr][sh * 16] = v0;
      *(uint4*)&sW[sr][sh * 16 + 8] = v1;
      const uint4* gx = (const uint4*)&h1T[(size_t)(i0 + sr) * 256 + kcol];
      uint4 x0 = gx[0], x1 = gx[1];
      unsigned rr[8] = {x0.x, x0.y, x0.z, x0.w, x1.x, x1.y, x1.z, x1.w};
      unsigned ww[8];
#pragma unroll
      for (int e = 0; e < 8; ++e) {  // BN1+relu fused while staging
        int ch = kcol + 2 * e;
        float f0 = bf2f((unsigned short)(rr[e] & 0xFFFFu));
        float f1 = bf2f((unsigned short)(rr[e] >> 16));
        f0 = fmaxf(fmaf(A[ch], f0, C[ch]), 0.f);
        f1 = fmaxf(fmaf(A[ch + 1], f1, C[ch + 1]), 0.f);
        ww[e] = (unsigned)f2bf(f0) | ((unsigned)f2bf(f1) << 16);
      }
      uint4 y0 = {ww[0], ww[1], ww[2], ww[3]};
      uint4 y1 = {ww[4], ww[5], ww[6], ww[7]};
      *(uint4*)&sX[sr][sh * 16] = y0;
      *(uint4*)&sX[sr][sh * 16 + 8] = y1;
    }
    __syncthreads();
    bf16x8 a[4], b[4];
#pragma unroll
    for (int tm = 0; tm < 4; ++tm)
      a[tm] = *(const bf16x8*)&sW[wc + tm * 16 + l15][g * 8];
#pragma unroll
    for (int tn = 0; tn < 4; ++tn)
      b[tn] = *(const bf16x8*)&sX[wn + tn * 16 + l15][g * 8];
#pragma unroll
    for (int tm = 0; tm < 4; ++tm)
#pragma unroll
      for (int tn = 0; tn < 4; ++tn)
        acc[tm][tn] = __builtin_amdgcn_mfma_f32_16x16x32_bf16(a[tm], b[tn], acc[tm][tn], 0, 0, 0);
  }
#pragma unroll
  for (int tm = 0; tm < 4; ++tm)
#pragma unroll
    for (int tn = 0; tn < 4; ++tn) {
      int c = wc + tm * 16 + g * 4;
      int n = i0 + wn + tn * 16 + l15;
      f32x4 v = acc[tm][tn];
      *(float4*)&o2[(size_t)n * 128 + c] = make_float4(v[0], v[1], v[2], v[3]);
    }
}

// final: out2T [i][128] + BN2 + relu -> d_out [B][128][16384] (transposed)
__global__ __launch_bounds__(256) void final_k(const float* __restrict__ o2,
                                               const float* __restrict__ A,
                                               const float* __restrict__ C,
                                               float* __restrict__ out) {
  __shared__ float tile[32][33];
  int b = blockIdx.z;
  int n0 = blockIdx.x * 32;
  int c0 = blockIdx.y * 32;
  int tx = threadIdx.x, ty = threadIdx.y;
  float a = A[c0 + tx], cc = C[c0 + tx];
  for (int r = ty; r < 32; r += 8) {
    float v = o2[(size_t)(b * 16384 + n0 + r) * 128 + c0 + tx];
    tile[r][tx] = fmaxf(fmaf(a, v, cc), 0.f);
  }
  __syncthreads();
  for (int r = ty; r < 32; r += 8)
    out[((size_t)(b * 128 + c0 + r)) * 16384 + n0 + tx] = tile[tx][r];
}

extern "C" void kernel_launch(void* const* d_in, const int* in_sizes, int n_in,
                              void* d_out, int out_size, void* d_ws, size_t ws_size,
                              hipStream_t stream) {
  const float* xyz1 = (const float*)d_in[0];
  const float* xyz2 = (const float*)d_in[1];
  const float* p1   = (const float*)d_in[2];
  const float* p2   = (const float*)d_in[3];
  const int*   idx1 = (const int*)d_in[4];
  const int*   idx2 = (const int*)d_in[5];
  const float* w1   = (const float*)d_in[6];
  // d_in[7]=b1, d_in[11]=b2: exactly absorbed by BN mean subtraction
  const float* g1   = (const float*)d_in[8];
  const float* be1  = (const float*)d_in[9];
  const float* w2   = (const float*)d_in[10];
  const float* g2   = (const float*)d_in[12];
  const float* be2  = (const float*)d_in[13];
  float* out = (float*)d_out;

  char* ws = (char*)d_ws;
  // idx3 | wgt | X 48MB | h1T 32MB (p2t bf16 8.4MB aliased, dead before
  // gemm1 writes) | o2 32MB (rec 25.2MB aliased, dead before gemm2 writes)
  // | w1b w2b part1 part2 params  => ~114MB
  int*            idx3 = (int*)(ws + 0x0);                      // 0.75MB
  float*          wgt  = (float*)(ws + 0xC0000);                // 0.75MB
  unsigned short* X    = (unsigned short*)(ws + 0x180000);      // 48MB
  unsigned short* h1T  = (unsigned short*)(ws + 0x3180000);     // 32MB
  unsigned short* p2t  = (unsigned short*)(ws + 0x3180000);     // alias h1T
  float*          o2   = (float*)(ws + 0x5180000);              // 32MB
  float*          rec  = (float*)(ws + 0x5180000);              // alias o2
  unsigned short* w1b  = (unsigned short*)(ws + 0x7180000);
  unsigned short* w2b  = (unsigned short*)(ws + 0x71B0000);
  float*          part1 = (float*)(ws + 0x71C0000);
  float*          part2 = (float*)(ws + 0x7240000);
  float*          a1   = (float*)(ws + 0x7280000);
  float*          c1   = a1 + 256;
  float*          a2   = c1 + 256;
  float*          c2   = a2 + 128;

  hipLaunchKernelGGL(transpose_k, dim3(128, 8, 4), dim3(32, 8), 0, stream, p2, p2t);
  hipLaunchKernelGGL(wcvt_k, dim3(512), dim3(256), 0, stream, w1, w2, w1b, w2b);
  hipLaunchKernelGGL(p1t_k, dim3(512, 4, 4), dim3(32, 8), 0, stream, p1, X);
  hipLaunchKernelGGL(knn_k, dim3(1024), dim3(256), 0, stream,
                     xyz1, xyz2, idx1, idx2, rec);
  hipLaunchKernelGGL(knnmerge_k, dim3(256), dim3(256), 0, stream, rec, idx3, wgt);
  hipLaunchKernelGGL(interp_k, dim3(512), dim3(256), 0, stream, p2t, idx3, wgt, X);
  hipLaunchKernelGGL(gemm1_k, dim3(512, 2), dim3(256), 0, stream, X, w1b, h1T);
  hipLaunchKernelGGL(bnstats1_k, dim3(256), dim3(256), 0, stream, h1T, part1);
  hipLaunchKernelGGL((bnfold_k<256>), dim3(1), dim3(256), 0, stream, part1, g1, be1, a1, c1);
  hipLaunchKernelGGL(gemm2_k, dim3(512), dim3(256), 0, stream, h1T, w2b, a1, c1, o2);
  hipLaunchKernelGGL(bnstats2_k, dim3(256), dim3(256), 0, stream, o2, part2);
  hipLaunchKernelGGL((bnfold_k<128>), dim3(1), dim3(256), 0, stream, part2, g2, be2, a2, c2);
  hipLaunchKernelGGL(final_k, dim3(512, 4, 4), dim3(32, 8), 0, stream, o2, a2, c2, out);
}

// Round 11
// 276.262 us; speedup vs baseline: 1.0112x; 1.0112x over previous
//
#include <hip/hip_runtime.h>
#include <hip/hip_bf16.h>

#define INF_F (__builtin_inff())

typedef __attribute__((ext_vector_type(8))) short bf16x8;
typedef __attribute__((ext_vector_type(4))) float f32x4;

__device__ __forceinline__ unsigned short f2bf(float f) {
  __hip_bfloat16 h = __float2bfloat16(f);
  return __builtin_bit_cast(unsigned short, h);
}
__device__ __forceinline__ float bf2f(unsigned short u) {
  return __uint_as_float((unsigned)u << 16);
}

// branchy sorted top-3 insert (scalar state only - R8 lesson: nothing
// address-taken). Strict < + ascending s = top_k lowest-index tie order.
#define TOP3_INS(d, sj, E0, E1, E2, J0, J1, J2)                      \
  {                                                                  \
    bool l0 = (d) < E0, l1 = (d) < E1;                               \
    E2 = l1 ? E1 : (d); J2 = l1 ? J1 : (sj);                         \
    E1 = l0 ? E0 : (l1 ? (d) : E1); J1 = l0 ? J0 : (l1 ? (sj) : J1); \
    E0 = l0 ? (d) : E0; J0 = l0 ? (sj) : J0;                         \
  }

// ---------------------------------------------------------------------------
// B=4, N=16384, S=4096, D1=128, D2=256, MLP=(256,128). M = B*N = 65536.
// X: [65536][384] bf16 (cols 0..127 = points1^T, 128..383 = interp)
// h1T: [65536][256] bf16 ; out2T: [65536][128] fp32.
// GEMMs: D[c][n] = W[c][k] * X[n][k] via mfma_f32_16x16x32_bf16.
// ---------------------------------------------------------------------------

// points2 [B][256][4096] fp32 -> p2t [B][4096][256] bf16 (coalesced gather rows)
__global__ __launch_bounds__(256) void transpose_k(const float* __restrict__ in,
                                                   unsigned short* __restrict__ out) {
  __shared__ float tile[32][33];
  int b = blockIdx.z;
  int s0 = blockIdx.x * 32;
  int k0 = blockIdx.y * 32;
  int tx = threadIdx.x, ty = threadIdx.y;  // 32 x 8
  const float* src = in + ((size_t)b * 256 + k0) * 4096 + s0;
  for (int r = ty; r < 32; r += 8) tile[r][tx] = src[(size_t)r * 4096 + tx];
  __syncthreads();
  unsigned short* dst = out + ((size_t)b * 4096 + s0) * 256 + k0;
  for (int r = ty; r < 32; r += 8) dst[(size_t)r * 256 + tx] = f2bf(tile[tx][r]);
}

// p1 [B][128][16384] fp32 -> X[b*16384+n][0..127] bf16 (transposed)
__global__ __launch_bounds__(256) void p1t_k(const float* __restrict__ p1,
                                             unsigned short* __restrict__ X) {
  __shared__ float tile[32][33];
  int b = blockIdx.z;
  int n0 = blockIdx.x * 32;
  int c0 = blockIdx.y * 32;
  int tx = threadIdx.x, ty = threadIdx.y;
  const float* src = p1 + ((size_t)b * 128 + c0) * 16384 + n0;
  for (int r = ty; r < 32; r += 8) tile[r][tx] = src[(size_t)r * 16384 + tx];
  __syncthreads();
  for (int r = ty; r < 32; r += 8)
    X[((size_t)(b * 16384 + n0 + r)) * 384 + c0 + tx] = f2bf(tile[tx][r]);
}

// w1 [256][384], w2 [128][256] fp32 -> bf16 copies (same layout)
__global__ __launch_bounds__(256) void wcvt_k(const float* __restrict__ w1,
                                              const float* __restrict__ w2,
                                              unsigned short* __restrict__ w1b,
                                              unsigned short* __restrict__ w2b) {
  int id = blockIdx.x * 256 + threadIdx.x;
  if (id < 98304) w1b[id] = f2bf(w1[id]);
  else w2b[id - 98304] = f2bf(w2[id - 98304]);
}

// pack sources: [B][4096] float4 {x,y,z,|p|^2 or 3e38 if batch-id mismatch}.
// 262KB total -> L2-resident for knn's uniform (scalar-pipe) reads.
__global__ __launch_bounds__(256) void pack_k(const float* __restrict__ xyz2,
                                              const int* __restrict__ idx1,
                                              const int* __restrict__ idx2,
                                              float4* __restrict__ pack) {
  int b = blockIdx.y;
  int s = blockIdx.x * 256 + threadIdx.x;  // 16 x-blocks
  float x = xyz2[(b * 3 + 0) * 4096 + s];
  float y = xyz2[(b * 3 + 1) * 4096 + s];
  float z = xyz2[(b * 3 + 2) * 4096 + s];
  float w = fmaf(x, x, fmaf(y, y, z * z));
  int common = idx1[b * 16384];
  w = (idx2[b * 4096 + s] == common) ? w : 3e38f;  // invalid -> d>BIG -> wgt 0
  pack[b * 4096 + s] = make_float4(x, y, z, w);
}

// 3-NN stage 1, scalar-pipe sources. 1024 blocks = 256 query-groups (256 q)
// x 4 S-slices (1024 src). 1 query/thread, NO LDS: the source read is
// wave-uniform from the packed array -> s_load on the scalar pipe (R6-R10
// lesson: ds_read_b128 at 12cyc/CU was an 82us floor at 1 q/thread).
// 64 states/wave => the insert branch truly skips (~50% of steps) unlike
// 256 states/wave where it was always taken (R9/R10). Hot step = 3 fma +
// 1 add + 1 cmp. Exact per-thread fallback if id != common (never here).
__global__ __launch_bounds__(256) void knn_k(const float* __restrict__ xyz1,
                                             const float* __restrict__ xyz2,
                                             const int* __restrict__ idx1,
                                             const int* __restrict__ idx2,
                                             const float4* __restrict__ pack,
                                             float* __restrict__ rec) {
  int bid = blockIdx.x;
  int qg = bid >> 2, sl = bid & 3;
  int b = qg >> 6;               // 64 query-groups per batch
  int nloc = (qg & 63) << 8;     // 256 queries per group
  int t = threadIdx.x;
  int n = nloc + t;
  int q0i = b * 16384 + n;
  int common = idx1[b * 16384];
  int sbase = sl << 10;
  const float4* ps = pack + b * 4096 + sbase;
  float px = xyz1[(b * 3 + 0) * 16384 + n];
  float py = xyz1[(b * 3 + 1) * 16384 + n];
  float pz = xyz1[(b * 3 + 2) * 16384 + n];
  int myid = idx1[q0i];
  float pn = fmaf(px, px, fmaf(py, py, pz * pz));
  float qx = -2.f * px, qy = -2.f * py, qz = -2.f * pz;
  float e0 = INF_F, e1 = INF_F, e2 = INF_F;
  int j0 = 0, j1 = 0, j2 = 0;
#pragma unroll 8
  for (int s = 0; s < 1024; ++s) {
    float4 p = ps[s];  // uniform addr -> scalar load (s_load_dwordx4/x16)
    float d = fmaf(qx, p.x, fmaf(qy, p.y, fmaf(qz, p.z, pn))) + p.w;
    if (__builtin_expect(d < e2, 0)) {  // skippable: 64 states/wave only
      int sj = sbase + s;
      TOP3_INS(d, sj, e0, e1, e2, j0, j1, j2);
    }
  }
  if (__builtin_expect(myid != common, 0)) {  // exact general-idx fallback
    e0 = INF_F; e1 = INF_F; e2 = INF_F; j0 = 0; j1 = 0; j2 = 0;
    for (int s = 0; s < 1024; ++s) {
      int gs = sbase + s;
      float x = xyz2[(b * 3 + 0) * 4096 + gs];
      float y = xyz2[(b * 3 + 1) * 4096 + gs];
      float z = xyz2[(b * 3 + 2) * 4096 + gs];
      float w = fmaf(x, x, fmaf(y, y, z * z));
      float d = fmaf(qx, x, fmaf(qy, y, fmaf(qz, z, pn))) + w;
      d = (idx2[b * 4096 + gs] == myid) ? d : INF_F;
      if (d < e2) TOP3_INS(d, gs, e0, e1, e2, j0, j1, j2);
    }
  }
  // rec layout [slice][query]: lane-consecutive 24B records => coalesced
  float* r = &rec[((size_t)sl * 65536 + q0i) * 6];
  r[0] = e0; r[1] = e1; r[2] = e2;
  ((int*)r)[3] = j0; ((int*)r)[4] = j1; ((int*)r)[5] = j2;
}

// 3-NN stage 2: merge 4 S-slice records (ascending slice order, lex (d,idx)
// = exact top_k tie semantics), compute inverse-distance weights.
__global__ __launch_bounds__(256) void knnmerge_k(const float* __restrict__ rec,
                                                  int* __restrict__ idx3,
                                                  float* __restrict__ wgt) {
  int i = blockIdx.x * 256 + threadIdx.x;  // 65536 queries
  float e0, e1, e2;
  int j0, j1, j2;
  {
    const float* r = &rec[(size_t)i * 6];
    e0 = r[0]; e1 = r[1]; e2 = r[2];
    j0 = ((const int*)r)[3]; j1 = ((const int*)r)[4]; j2 = ((const int*)r)[5];
  }
#pragma unroll
  for (int c = 1; c < 4; ++c) {
    const float* r = &rec[((size_t)c * 65536 + i) * 6];
    const int* ir = (const int*)r;
#pragma unroll
    for (int w = 0; w < 3; ++w) {
      float d = r[w];
      int sj = ir[3 + w];
      bool l0 = (d < e0) || (d == e0 && sj < j0);
      bool l1 = (d < e1) || (d == e1 && sj < j1);
      bool l2 = (d < e2) || (d == e2 && sj < j2);
      e2 = l1 ? e1 : (l2 ? d : e2);
      j2 = l1 ? j1 : (l2 ? sj : j2);
      e1 = l0 ? e0 : (l1 ? d : e1);
      j1 = l0 ? j0 : (l1 ? sj : j1);
      e0 = l0 ? d : e0;
      j0 = l0 ? sj : j0;
    }
  }
  float r0 = 1.f / (e0 + 1e-8f);
  float r1 = 1.f / (e1 + 1e-8f);
  float r2 = 1.f / (e2 + 1e-8f);
  float rs = r0 + r1 + r2;
  float w0 = (e0 > 1e8f) ? 0.f : r0 / rs;  // ref: where(d3>BIG,0)+nan_to_num
  float w1 = (e1 > 1e8f) ? 0.f : r1 / rs;
  float w2 = (e2 > 1e8f) ? 0.f : r2 / rs;
  idx3[(size_t)i * 3 + 0] = j0; idx3[(size_t)i * 3 + 1] = j1; idx3[(size_t)i * 3 + 2] = j2;
  wgt[(size_t)i * 3 + 0] = w0;  wgt[(size_t)i * 3 + 1] = w1;  wgt[(size_t)i * 3 + 2] = w2;
}

// interp (bf16 p2t rows) -> X[i][128+k] bf16
__global__ __launch_bounds__(256) void interp_k(const unsigned short* __restrict__ p2t,
                                                const int* __restrict__ idx3,
                                                const float* __restrict__ wgt,
                                                unsigned short* __restrict__ X) {
  int i0 = blockIdx.x * 128;
  int b = i0 >> 14;
  int k = threadIdx.x;
  const unsigned short* base = p2t + (size_t)b * 4096 * 256;
#pragma unroll 2
  for (int ii = 0; ii < 128; ++ii) {
    int i = i0 + ii;
    int id0 = idx3[i * 3 + 0], id1 = idx3[i * 3 + 1], id2 = idx3[i * 3 + 2];
    float w0 = wgt[i * 3 + 0], w1v = wgt[i * 3 + 1], w2v = wgt[i * 3 + 2];
    float v = w0 * bf2f(base[id0 * 256 + k]);
    v = fmaf(w1v, bf2f(base[id1 * 256 + k]), v);
    v = fmaf(w2v, bf2f(base[id2 * 256 + k]), v);
    X[(size_t)i * 384 + 128 + k] = f2bf(v);
  }
}

// GEMM1 (MFMA): h1T[n][c] = sum_k w1[c][k] X[n][k]. 128x128 tile, BK=32,
// K=384. grid (512, 2).
__global__ __launch_bounds__(256) void gemm1_k(const unsigned short* __restrict__ X,
                                               const unsigned short* __restrict__ Wb,
                                               unsigned short* __restrict__ h1T) {
  __shared__ unsigned short sW[128][40];
  __shared__ unsigned short sX[128][40];
  int t = threadIdx.x;
  int i0 = blockIdx.x * 128;
  int c0 = blockIdx.y * 128;
  int w = t >> 6, lane = t & 63;
  int wc = (w & 1) * 64, wn = (w >> 1) * 64;
  int l15 = lane & 15, g = lane >> 4;
  f32x4 acc[4][4];
#pragma unroll
  for (int a = 0; a < 4; ++a)
#pragma unroll
    for (int bq = 0; bq < 4; ++bq) acc[a][bq] = (f32x4)0.f;
  int sr = t & 127, sh = t >> 7;
  for (int kc = 0; kc < 12; ++kc) {
    int k0 = kc * 32;
    __syncthreads();
    {
      const uint4* gw = (const uint4*)&Wb[(size_t)(c0 + sr) * 384 + k0 + sh * 16];
      uint4 v0 = gw[0], v1 = gw[1];
      *(uint4*)&sW[sr][sh * 16] = v0;
      *(uint4*)&sW[sr][sh * 16 + 8] = v1;
      const uint4* gx = (const uint4*)&X[(size_t)(i0 + sr) * 384 + k0 + sh * 16];
      uint4 x0 = gx[0], x1 = gx[1];
      *(uint4*)&sX[sr][sh * 16] = x0;
      *(uint4*)&sX[sr][sh * 16 + 8] = x1;
    }
    __syncthreads();
    bf16x8 a[4], b[4];
#pragma unroll
    for (int tm = 0; tm < 4; ++tm)
      a[tm] = *(const bf16x8*)&sW[wc + tm * 16 + l15][g * 8];
#pragma unroll
    for (int tn = 0; tn < 4; ++tn)
      b[tn] = *(const bf16x8*)&sX[wn + tn * 16 + l15][g * 8];
#pragma unroll
    for (int tm = 0; tm < 4; ++tm)
#pragma unroll
      for (int tn = 0; tn < 4; ++tn)
        acc[tm][tn] = __builtin_amdgcn_mfma_f32_16x16x32_bf16(a[tm], b[tn], acc[tm][tn], 0, 0, 0);
  }
#pragma unroll
  for (int tm = 0; tm < 4; ++tm)
#pragma unroll
    for (int tn = 0; tn < 4; ++tn) {
      int c = c0 + wc + tm * 16 + g * 4;
      int n = i0 + wn + tn * 16 + l15;
      f32x4 v = acc[tm][tn];
      ushort4 o;
      o.x = f2bf(v[0]); o.y = f2bf(v[1]); o.z = f2bf(v[2]); o.w = f2bf(v[3]);
      *(ushort4*)&h1T[(size_t)n * 256 + c] = o;
    }
}

// BN1 stats over h1T bf16 [65536][256]
__global__ __launch_bounds__(256) void bnstats1_k(const unsigned short* __restrict__ h,
                                                  float* __restrict__ part) {
  int t = threadIdx.x, q = t & 63, ro = t >> 6;
  int r0 = blockIdx.x * 256;
  float s0 = 0, s1 = 0, s2 = 0, s3 = 0, q0 = 0, q1 = 0, q2 = 0, q3 = 0;
  for (int it = 0; it < 64; ++it) {
    size_t r = r0 + it * 4 + ro;
    ushort4 v = *(const ushort4*)&h[r * 256 + q * 4];
    float f0 = bf2f(v.x), f1 = bf2f(v.y), f2 = bf2f(v.z), f3 = bf2f(v.w);
    s0 += f0; q0 += f0 * f0;
    s1 += f1; q1 += f1 * f1;
    s2 += f2; q2 += f2 * f2;
    s3 += f3; q3 += f3 * f3;
  }
  __shared__ float sm[256][8];
  sm[t][0] = s0; sm[t][1] = s1; sm[t][2] = s2; sm[t][3] = s3;
  sm[t][4] = q0; sm[t][5] = q1; sm[t][6] = q2; sm[t][7] = q3;
  __syncthreads();
  if (t < 64) {
#pragma unroll
    for (int j = 1; j < 4; ++j)
#pragma unroll
      for (int e = 0; e < 8; ++e) sm[t][e] += sm[t + 64 * j][e];
#pragma unroll
    for (int i = 0; i < 4; ++i) {
      part[((size_t)blockIdx.x * 256 + t * 4 + i) * 2 + 0] = sm[t][i];
      part[((size_t)blockIdx.x * 256 + t * 4 + i) * 2 + 1] = sm[t][4 + i];
    }
  }
}

// BN2 stats over out2T fp32 [65536][128]
__global__ __launch_bounds__(256) void bnstats2_k(const float* __restrict__ o2,
                                                  float* __restrict__ part) {
  int t = threadIdx.x, q = t & 31, ro = t >> 5;
  int r0 = blockIdx.x * 256;
  float s0 = 0, s1 = 0, s2 = 0, s3 = 0, q0 = 0, q1 = 0, q2 = 0, q3 = 0;
  for (int it = 0; it < 32; ++it) {
    size_t r = r0 + it * 8 + ro;
    float4 v = *(const float4*)&o2[r * 128 + q * 4];
    s0 += v.x; q0 += v.x * v.x;
    s1 += v.y; q1 += v.y * v.y;
    s2 += v.z; q2 += v.z * v.z;
    s3 += v.w; q3 += v.w * v.w;
  }
  __shared__ float sm[256][8];
  sm[t][0] = s0; sm[t][1] = s1; sm[t][2] = s2; sm[t][3] = s3;
  sm[t][4] = q0; sm[t][5] = q1; sm[t][6] = q2; sm[t][7] = q3;
  __syncthreads();
  if (t < 32) {
#pragma unroll
    for (int j = 1; j < 8; ++j)
#pragma unroll
      for (int e = 0; e < 8; ++e) sm[t][e] += sm[t + 32 * j][e];
#pragma unroll
    for (int i = 0; i < 4; ++i) {
      part[((size_t)blockIdx.x * 128 + t * 4 + i) * 2 + 0] = sm[t][i];
      part[((size_t)blockIdx.x * 128 + t * 4 + i) * 2 + 1] = sm[t][4 + i];
    }
  }
}

// fold partials -> per-channel a*x + c
template <int C>
__global__ __launch_bounds__(256) void bnfold_k(const float* __restrict__ part,
                                                const float* __restrict__ g,
                                                const float* __restrict__ be,
                                                float* __restrict__ A,
                                                float* __restrict__ Cc) {
  int c = threadIdx.x;
  if (c >= C) return;
  float s1 = 0.f, s2 = 0.f;
  for (int b = 0; b < 256; ++b) {
    s1 += part[((size_t)b * C + c) * 2 + 0];
    s2 += part[((size_t)b * C + c) * 2 + 1];
  }
  float mean = s1 * (1.f / 65536.f);
  float var = s2 * (1.f / 65536.f) - mean * mean;  // biased, as torch BN
  float a = g[c] * rsqrtf(var + 1e-5f);
  A[c] = a;
  Cc[c] = be[c] - mean * a;
}

// GEMM2 (MFMA) with fused BN1+ReLU on staging: out2T[n][c2] =
// sum_k w2[c2][k] relu(a1[k]*h1T[n][k]+c1[k]). K=256. grid (512).
__global__ __launch_bounds__(256) void gemm2_k(const unsigned short* __restrict__ h1T,
                                               const unsigned short* __restrict__ Wb,
                                               const float* __restrict__ A,
                                               const float* __restrict__ C,
                                               float* __restrict__ o2) {
  __shared__ unsigned short sW[128][40];
  __shared__ unsigned short sX[128][40];
  int t = threadIdx.x;
  int i0 = blockIdx.x * 128;
  int w = t >> 6, lane = t & 63;
  int wc = (w & 1) * 64, wn = (w >> 1) * 64;
  int l15 = lane & 15, g = lane >> 4;
  f32x4 acc[4][4];
#pragma unroll
  for (int a = 0; a < 4; ++a)
#pragma unroll
    for (int bq = 0; bq < 4; ++bq) acc[a][bq] = (f32x4)0.f;
  int sr = t & 127, sh = t >> 7;
  for (int kc = 0; kc < 8; ++kc) {
    int k0 = kc * 32;
    int kcol = k0 + sh * 16;
    __syncthreads();
    {
      const uint4* gw = (const uint4*)&Wb[(size_t)sr * 256 + kcol];
      uint4 v0 = gw[0], v1 = gw[1];
      *(uint4*)&sW[sr][sh * 16] = v0;
      *(uint4*)&sW[sr][sh * 16 + 8] = v1;
      const uint4* gx = (const uint4*)&h1T[(size_t)(i0 + sr) * 256 + kcol];
      uint4 x0 = gx[0], x1 = gx[1];
      unsigned rr[8] = {x0.x, x0.y, x0.z, x0.w, x1.x, x1.y, x1.z, x1.w};
      unsigned ww[8];
#pragma unroll
      for (int e = 0; e < 8; ++e) {  // BN1+relu fused while staging
        int ch = kcol + 2 * e;
        float f0 = bf2f((unsigned short)(rr[e] & 0xFFFFu));
        float f1 = bf2f((unsigned short)(rr[e] >> 16));
        f0 = fmaxf(fmaf(A[ch], f0, C[ch]), 0.f);
        f1 = fmaxf(fmaf(A[ch + 1], f1, C[ch + 1]), 0.f);
        ww[e] = (unsigned)f2bf(f0) | ((unsigned)f2bf(f1) << 16);
      }
      uint4 y0 = {ww[0], ww[1], ww[2], ww[3]};
      uint4 y1 = {ww[4], ww[5], ww[6], ww[7]};
      *(uint4*)&sX[sr][sh * 16] = y0;
      *(uint4*)&sX[sr][sh * 16 + 8] = y1;
    }
    __syncthreads();
    bf16x8 a[4], b[4];
#pragma unroll
    for (int tm = 0; tm < 4; ++tm)
      a[tm] = *(const bf16x8*)&sW[wc + tm * 16 + l15][g * 8];
#pragma unroll
    for (int tn = 0; tn < 4; ++tn)
      b[tn] = *(const bf16x8*)&sX[wn + tn * 16 + l15][g * 8];
#pragma unroll
    for (int tm = 0; tm < 4; ++tm)
#pragma unroll
      for (int tn = 0; tn < 4; ++tn)
        acc[tm][tn] = __builtin_amdgcn_mfma_f32_16x16x32_bf16(a[tm], b[tn], acc[tm][tn], 0, 0, 0);
  }
#pragma unroll
  for (int tm = 0; tm < 4; ++tm)
#pragma unroll
    for (int tn = 0; tn < 4; ++tn) {
      int c = wc + tm * 16 + g * 4;
      int n = i0 + wn + tn * 16 + l15;
      f32x4 v = acc[tm][tn];
      *(float4*)&o2[(size_t)n * 128 + c] = make_float4(v[0], v[1], v[2], v[3]);
    }
}

// final: out2T [i][128] + BN2 + relu -> d_out [B][128][16384] (transposed)
__global__ __launch_bounds__(256) void final_k(const float* __restrict__ o2,
                                               const float* __restrict__ A,
                                               const float* __restrict__ C,
                                               float* __restrict__ out) {
  __shared__ float tile[32][33];
  int b = blockIdx.z;
  int n0 = blockIdx.x * 32;
  int c0 = blockIdx.y * 32;
  int tx = threadIdx.x, ty = threadIdx.y;
  float a = A[c0 + tx], cc = C[c0 + tx];
  for (int r = ty; r < 32; r += 8) {
    float v = o2[(size_t)(b * 16384 + n0 + r) * 128 + c0 + tx];
    tile[r][tx] = fmaxf(fmaf(a, v, cc), 0.f);
  }
  __syncthreads();
  for (int r = ty; r < 32; r += 8)
    out[((size_t)(b * 128 + c0 + r)) * 16384 + n0 + tx] = tile[tx][r];
}

extern "C" void kernel_launch(void* const* d_in, const int* in_sizes, int n_in,
                              void* d_out, int out_size, void* d_ws, size_t ws_size,
                              hipStream_t stream) {
  const float* xyz1 = (const float*)d_in[0];
  const float* xyz2 = (const float*)d_in[1];
  const float* p1   = (const float*)d_in[2];
  const float* p2   = (const float*)d_in[3];
  const int*   idx1 = (const int*)d_in[4];
  const int*   idx2 = (const int*)d_in[5];
  const float* w1   = (const float*)d_in[6];
  // d_in[7]=b1, d_in[11]=b2: exactly absorbed by BN mean subtraction
  const float* g1   = (const float*)d_in[8];
  const float* be1  = (const float*)d_in[9];
  const float* w2   = (const float*)d_in[10];
  const float* g2   = (const float*)d_in[12];
  const float* be2  = (const float*)d_in[13];
  float* out = (float*)d_out;

  char* ws = (char*)d_ws;
  // idx3 | wgt | X 48MB | h1T 32MB (p2t bf16 8.4MB aliased, dead before
  // gemm1 writes) | o2 32MB (rec 6.3MB aliased, dead before gemm2 writes)
  // | w1b w2b part1 part2 pack 262KB params  => ~114MB
  int*            idx3 = (int*)(ws + 0x0);                      // 0.75MB
  float*          wgt  = (float*)(ws + 0xC0000);                // 0.75MB
  unsigned short* X    = (unsigned short*)(ws + 0x180000);      // 48MB
  unsigned short* h1T  = (unsigned short*)(ws + 0x3180000);     // 32MB
  unsigned short* p2t  = (unsigned short*)(ws + 0x3180000);     // alias h1T
  float*          o2   = (float*)(ws + 0x5180000);              // 32MB
  float*          rec  = (float*)(ws + 0x5180000);              // alias o2
  unsigned short* w1b  = (unsigned short*)(ws + 0x7180000);
  unsigned short* w2b  = (unsigned short*)(ws + 0x71B0000);
  float*          part1 = (float*)(ws + 0x71C0000);
  float*          part2 = (float*)(ws + 0x7240000);
  float4*         pack = (float4*)(ws + 0x7280000);             // 262KB
  float*          a1   = (float*)(ws + 0x72C8000);
  float*          c1   = a1 + 256;
  float*          a2   = c1 + 256;
  float*          c2   = a2 + 128;

  hipLaunchKernelGGL(transpose_k, dim3(128, 8, 4), dim3(32, 8), 0, stream, p2, p2t);
  hipLaunchKernelGGL(wcvt_k, dim3(512), dim3(256), 0, stream, w1, w2, w1b, w2b);
  hipLaunchKernelGGL(p1t_k, dim3(512, 4, 4), dim3(32, 8), 0, stream, p1, X);
  hipLaunchKernelGGL(pack_k, dim3(16, 4), dim3(256), 0, stream, xyz2, idx1, idx2, pack);
  hipLaunchKernelGGL(knn_k, dim3(1024), dim3(256), 0, stream,
                     xyz1, xyz2, idx1, idx2, pack, rec);
  hipLaunchKernelGGL(knnmerge_k, dim3(256), dim3(256), 0, stream, rec, idx3, wgt);
  hipLaunchKernelGGL(interp_k, dim3(512), dim3(256), 0, stream, p2t, idx3, wgt, X);
  hipLaunchKernelGGL(gemm1_k, dim3(512, 2), dim3(256), 0, stream, X, w1b, h1T);
  hipLaunchKernelGGL(bnstats1_k, dim3(256), dim3(256), 0, stream, h1T, part1);
  hipLaunchKernelGGL((bnfold_k<256>), dim3(1), dim3(256), 0, stream, part1, g1, be1, a1, c1);
  hipLaunchKernelGGL(gemm2_k, dim3(512), dim3(256), 0, stream, h1T, w2b, a1, c1, o2);
  hipLaunchKernelGGL(bnstats2_k, dim3(256), dim3(256), 0, stream, o2, part2);
  hipLaunchKernelGGL((bnfold_k<128>), dim3(1), dim3(256), 0, stream, part2, g2, be2, a2, c2);
  hipLaunchKernelGGL(final_k, dim3(512, 4, 4), dim3(32, 8), 0, stream, o2, a2, c2, out);
}

// Round 12
// 260.400 us; speedup vs baseline: 1.0728x; 1.0609x over previous
//
#include <hip/hip_runtime.h>
#include <hip/hip_bf16.h>

#define INF_F (__builtin_inff())

typedef __attribute__((ext_vector_type(8))) short bf16x8;
typedef __attribute__((ext_vector_type(4))) float f32x4;

__device__ __forceinline__ unsigned short f2bf(float f) {
  __hip_bfloat16 h = __float2bfloat16(f);
  return __builtin_bit_cast(unsigned short, h);
}
__device__ __forceinline__ float bf2f(unsigned short u) {
  return __uint_as_float((unsigned)u << 16);
}

// branchy sorted top-3 insert (scalar state only - R8 lesson: nothing
// address-taken). Strict < + ascending s = top_k lowest-index tie order.
#define TOP3_INS(d, sj, E0, E1, E2, J0, J1, J2)                      \
  {                                                                  \
    bool l0 = (d) < E0, l1 = (d) < E1;                               \
    E2 = l1 ? E1 : (d); J2 = l1 ? J1 : (sj);                         \
    E1 = l0 ? E0 : (l1 ? (d) : E1); J1 = l0 ? J0 : (l1 ? (sj) : J1); \
    E0 = l0 ? (d) : E0; J0 = l0 ? (sj) : J0;                         \
  }

// ---------------------------------------------------------------------------
// B=4, N=16384, S=4096, D1=128, D2=256, MLP=(256,128). M = B*N = 65536.
// X: [65536][384] bf16 (cols 0..127 = points1^T, 128..383 = interp)
// h1T: [65536][256] bf16 ; out2T: [65536][128] fp32.
// GEMMs: D[c][n] = W[c][k] * X[n][k] via mfma_f32_16x16x32_bf16.
// ---------------------------------------------------------------------------

// points2 [B][256][4096] fp32 -> p2t [B][4096][256] bf16 (coalesced gather rows)
__global__ __launch_bounds__(256) void transpose_k(const float* __restrict__ in,
                                                   unsigned short* __restrict__ out) {
  __shared__ float tile[32][33];
  int b = blockIdx.z;
  int s0 = blockIdx.x * 32;
  int k0 = blockIdx.y * 32;
  int tx = threadIdx.x, ty = threadIdx.y;  // 32 x 8
  const float* src = in + ((size_t)b * 256 + k0) * 4096 + s0;
  for (int r = ty; r < 32; r += 8) tile[r][tx] = src[(size_t)r * 4096 + tx];
  __syncthreads();
  unsigned short* dst = out + ((size_t)b * 4096 + s0) * 256 + k0;
  for (int r = ty; r < 32; r += 8) dst[(size_t)r * 256 + tx] = f2bf(tile[tx][r]);
}

// p1 [B][128][16384] fp32 -> X[b*16384+n][0..127] bf16 (transposed)
__global__ __launch_bounds__(256) void p1t_k(const float* __restrict__ p1,
                                             unsigned short* __restrict__ X) {
  __shared__ float tile[32][33];
  int b = blockIdx.z;
  int n0 = blockIdx.x * 32;
  int c0 = blockIdx.y * 32;
  int tx = threadIdx.x, ty = threadIdx.y;
  const float* src = p1 + ((size_t)b * 128 + c0) * 16384 + n0;
  for (int r = ty; r < 32; r += 8) tile[r][tx] = src[(size_t)r * 16384 + tx];
  __syncthreads();
  for (int r = ty; r < 32; r += 8)
    X[((size_t)(b * 16384 + n0 + r)) * 384 + c0 + tx] = f2bf(tile[tx][r]);
}

// fused: w1/w2 fp32->bf16 copies + source packing.
// ids 0..98303 -> w1b, 98304..131071 -> w2b, 131072..147455 -> pack entry.
// pack: [B][4096] float4 {x,y,z,|p|^2 or 3e38 if batch-id mismatch}; 262KB
// -> L2/L3-resident for knn's uniform scalar-pipe reads.
__global__ __launch_bounds__(256) void wcvtpack_k(const float* __restrict__ w1,
                                                  const float* __restrict__ w2,
                                                  const float* __restrict__ xyz2,
                                                  const int* __restrict__ idx1,
                                                  const int* __restrict__ idx2,
                                                  unsigned short* __restrict__ w1b,
                                                  unsigned short* __restrict__ w2b,
                                                  float4* __restrict__ pack) {
  int id = blockIdx.x * 256 + threadIdx.x;  // 576 blocks = 147456 ids
  if (id < 98304) {
    w1b[id] = f2bf(w1[id]);
  } else if (id < 131072) {
    w2b[id - 98304] = f2bf(w2[id - 98304]);
  } else {
    int pid = id - 131072;
    int b = pid >> 12, s = pid & 4095;
    float x = xyz2[(b * 3 + 0) * 4096 + s];
    float y = xyz2[(b * 3 + 1) * 4096 + s];
    float z = xyz2[(b * 3 + 2) * 4096 + s];
    float w = fmaf(x, x, fmaf(y, y, z * z));
    int common = idx1[b * 16384];
    w = (idx2[b * 4096 + s] == common) ? w : 3e38f;  // invalid -> d>BIG -> wgt 0
    pack[b * 4096 + s] = make_float4(x, y, z, w);
  }
}

// 3-NN stage 1, scalar-pipe sources. 2048 blocks = 256 query-groups (256 q)
// x 8 S-slices (512 src). 1 query/thread, NO LDS, VGPR ~12 -> occupancy cap
// is the GRID (R11: 1024 blocks = 16 waves/CU = 42% occ, VALUBusy 57%).
// 8 blocks/CU -> 32 waves/CU. Warmup cost rises (~62% vs 41% taken steps,
// +27% VALU) but 2x wave pool on a 43%-idle VALU nets a win.
// Exact per-thread fallback if id != common (never taken on this data).
__global__ __launch_bounds__(256) void knn_k(const float* __restrict__ xyz1,
                                             const float* __restrict__ xyz2,
                                             const int* __restrict__ idx1,
                                             const int* __restrict__ idx2,
                                             const float4* __restrict__ pack,
                                             float* __restrict__ rec) {
  int bid = blockIdx.x;
  int qg = bid >> 3, sl = bid & 7;
  int b = qg >> 6;               // 64 query-groups per batch
  int nloc = (qg & 63) << 8;     // 256 queries per group
  int t = threadIdx.x;
  int n = nloc + t;
  int q0i = b * 16384 + n;
  int common = idx1[b * 16384];
  int sbase = sl << 9;           // 512-source slice
  const float4* ps = pack + b * 4096 + sbase;
  float px = xyz1[(b * 3 + 0) * 16384 + n];
  float py = xyz1[(b * 3 + 1) * 16384 + n];
  float pz = xyz1[(b * 3 + 2) * 16384 + n];
  int myid = idx1[q0i];
  float pn = fmaf(px, px, fmaf(py, py, pz * pz));
  float qx = -2.f * px, qy = -2.f * py, qz = -2.f * pz;
  float e0 = INF_F, e1 = INF_F, e2 = INF_F;
  int j0 = 0, j1 = 0, j2 = 0;
#pragma unroll 8
  for (int s = 0; s < 512; ++s) {
    float4 p = ps[s];  // uniform addr -> scalar load (s_load_dwordx4/x16)
    float d = fmaf(qx, p.x, fmaf(qy, p.y, fmaf(qz, p.z, pn))) + p.w;
    if (__builtin_expect(d < e2, 0)) {  // 64 states/wave: genuinely skippable
      int sj = sbase + s;
      TOP3_INS(d, sj, e0, e1, e2, j0, j1, j2);
    }
  }
  if (__builtin_expect(myid != common, 0)) {  // exact general-idx fallback
    e0 = INF_F; e1 = INF_F; e2 = INF_F; j0 = 0; j1 = 0; j2 = 0;
    for (int s = 0; s < 512; ++s) {
      int gs = sbase + s;
      float x = xyz2[(b * 3 + 0) * 4096 + gs];
      float y = xyz2[(b * 3 + 1) * 4096 + gs];
      float z = xyz2[(b * 3 + 2) * 4096 + gs];
      float w = fmaf(x, x, fmaf(y, y, z * z));
      float d = fmaf(qx, x, fmaf(qy, y, fmaf(qz, z, pn))) + w;
      d = (idx2[b * 4096 + gs] == myid) ? d : INF_F;
      if (d < e2) TOP3_INS(d, gs, e0, e1, e2, j0, j1, j2);
    }
  }
  // rec layout [slice][query]: lane-consecutive 24B records => coalesced
  float* r = &rec[((size_t)sl * 65536 + q0i) * 6];
  r[0] = e0; r[1] = e1; r[2] = e2;
  ((int*)r)[3] = j0; ((int*)r)[4] = j1; ((int*)r)[5] = j2;
}

// 3-NN stage 2: merge 8 S-slice records (ascending slice order, lex (d,idx)
// = exact top_k tie semantics), compute inverse-distance weights.
__global__ __launch_bounds__(256) void knnmerge_k(const float* __restrict__ rec,
                                                  int* __restrict__ idx3,
                                                  float* __restrict__ wgt) {
  int i = blockIdx.x * 256 + threadIdx.x;  // 65536 queries
  float e0, e1, e2;
  int j0, j1, j2;
  {
    const float* r = &rec[(size_t)i * 6];
    e0 = r[0]; e1 = r[1]; e2 = r[2];
    j0 = ((const int*)r)[3]; j1 = ((const int*)r)[4]; j2 = ((const int*)r)[5];
  }
#pragma unroll
  for (int c = 1; c < 8; ++c) {
    const float* r = &rec[((size_t)c * 65536 + i) * 6];
    const int* ir = (const int*)r;
#pragma unroll
    for (int w = 0; w < 3; ++w) {
      float d = r[w];
      int sj = ir[3 + w];
      bool l0 = (d < e0) || (d == e0 && sj < j0);
      bool l1 = (d < e1) || (d == e1 && sj < j1);
      bool l2 = (d < e2) || (d == e2 && sj < j2);
      e2 = l1 ? e1 : (l2 ? d : e2);
      j2 = l1 ? j1 : (l2 ? sj : j2);
      e1 = l0 ? e0 : (l1 ? d : e1);
      j1 = l0 ? j0 : (l1 ? sj : j1);
      e0 = l0 ? d : e0;
      j0 = l0 ? sj : j0;
    }
  }
  float r0 = 1.f / (e0 + 1e-8f);
  float r1 = 1.f / (e1 + 1e-8f);
  float r2 = 1.f / (e2 + 1e-8f);
  float rs = r0 + r1 + r2;
  float w0 = (e0 > 1e8f) ? 0.f : r0 / rs;  // ref: where(d3>BIG,0)+nan_to_num
  float w1 = (e1 > 1e8f) ? 0.f : r1 / rs;
  float w2 = (e2 > 1e8f) ? 0.f : r2 / rs;
  idx3[(size_t)i * 3 + 0] = j0; idx3[(size_t)i * 3 + 1] = j1; idx3[(size_t)i * 3 + 2] = j2;
  wgt[(size_t)i * 3 + 0] = w0;  wgt[(size_t)i * 3 + 1] = w1;  wgt[(size_t)i * 3 + 2] = w2;
}

// interp (bf16 p2t rows) -> X[i][128+k] bf16
__global__ __launch_bounds__(256) void interp_k(const unsigned short* __restrict__ p2t,
                                                const int* __restrict__ idx3,
                                                const float* __restrict__ wgt,
                                                unsigned short* __restrict__ X) {
  int i0 = blockIdx.x * 128;
  int b = i0 >> 14;
  int k = threadIdx.x;
  const unsigned short* base = p2t + (size_t)b * 4096 * 256;
#pragma unroll 2
  for (int ii = 0; ii < 128; ++ii) {
    int i = i0 + ii;
    int id0 = idx3[i * 3 + 0], id1 = idx3[i * 3 + 1], id2 = idx3[i * 3 + 2];
    float w0 = wgt[i * 3 + 0], w1v = wgt[i * 3 + 1], w2v = wgt[i * 3 + 2];
    float v = w0 * bf2f(base[id0 * 256 + k]);
    v = fmaf(w1v, bf2f(base[id1 * 256 + k]), v);
    v = fmaf(w2v, bf2f(base[id2 * 256 + k]), v);
    X[(size_t)i * 384 + 128 + k] = f2bf(v);
  }
}

// GEMM1 (MFMA): h1T[n][c] = sum_k w1[c][k] X[n][k]. 128x128 tile, BK=32,
// K=384. grid (512, 2).
__global__ __launch_bounds__(256) void gemm1_k(const unsigned short* __restrict__ X,
                                               const unsigned short* __restrict__ Wb,
                                               unsigned short* __restrict__ h1T) {
  __shared__ unsigned short sW[128][40];
  __shared__ unsigned short sX[128][40];
  int t = threadIdx.x;
  int i0 = blockIdx.x * 128;
  int c0 = blockIdx.y * 128;
  int w = t >> 6, lane = t & 63;
  int wc = (w & 1) * 64, wn = (w >> 1) * 64;
  int l15 = lane & 15, g = lane >> 4;
  f32x4 acc[4][4];
#pragma unroll
  for (int a = 0; a < 4; ++a)
#pragma unroll
    for (int bq = 0; bq < 4; ++bq) acc[a][bq] = (f32x4)0.f;
  int sr = t & 127, sh = t >> 7;
  for (int kc = 0; kc < 12; ++kc) {
    int k0 = kc * 32;
    __syncthreads();
    {
      const uint4* gw = (const uint4*)&Wb[(size_t)(c0 + sr) * 384 + k0 + sh * 16];
      uint4 v0 = gw[0], v1 = gw[1];
      *(uint4*)&sW[sr][sh * 16] = v0;
      *(uint4*)&sW[sr][sh * 16 + 8] = v1;
      const uint4* gx = (const uint4*)&X[(size_t)(i0 + sr) * 384 + k0 + sh * 16];
      uint4 x0 = gx[0], x1 = gx[1];
      *(uint4*)&sX[sr][sh * 16] = x0;
      *(uint4*)&sX[sr][sh * 16 + 8] = x1;
    }
    __syncthreads();
    bf16x8 a[4], b[4];
#pragma unroll
    for (int tm = 0; tm < 4; ++tm)
      a[tm] = *(const bf16x8*)&sW[wc + tm * 16 + l15][g * 8];
#pragma unroll
    for (int tn = 0; tn < 4; ++tn)
      b[tn] = *(const bf16x8*)&sX[wn + tn * 16 + l15][g * 8];
#pragma unroll
    for (int tm = 0; tm < 4; ++tm)
#pragma unroll
      for (int tn = 0; tn < 4; ++tn)
        acc[tm][tn] = __builtin_amdgcn_mfma_f32_16x16x32_bf16(a[tm], b[tn], acc[tm][tn], 0, 0, 0);
  }
#pragma unroll
  for (int tm = 0; tm < 4; ++tm)
#pragma unroll
    for (int tn = 0; tn < 4; ++tn) {
      int c = c0 + wc + tm * 16 + g * 4;
      int n = i0 + wn + tn * 16 + l15;
      f32x4 v = acc[tm][tn];
      ushort4 o;
      o.x = f2bf(v[0]); o.y = f2bf(v[1]); o.z = f2bf(v[2]); o.w = f2bf(v[3]);
      *(ushort4*)&h1T[(size_t)n * 256 + c] = o;
    }
}

// BN1 stats over h1T bf16 [65536][256]
__global__ __launch_bounds__(256) void bnstats1_k(const unsigned short* __restrict__ h,
                                                  float* __restrict__ part) {
  int t = threadIdx.x, q = t & 63, ro = t >> 6;
  int r0 = blockIdx.x * 256;
  float s0 = 0, s1 = 0, s2 = 0, s3 = 0, q0 = 0, q1 = 0, q2 = 0, q3 = 0;
  for (int it = 0; it < 64; ++it) {
    size_t r = r0 + it * 4 + ro;
    ushort4 v = *(const ushort4*)&h[r * 256 + q * 4];
    float f0 = bf2f(v.x), f1 = bf2f(v.y), f2 = bf2f(v.z), f3 = bf2f(v.w);
    s0 += f0; q0 += f0 * f0;
    s1 += f1; q1 += f1 * f1;
    s2 += f2; q2 += f2 * f2;
    s3 += f3; q3 += f3 * f3;
  }
  __shared__ float sm[256][8];
  sm[t][0] = s0; sm[t][1] = s1; sm[t][2] = s2; sm[t][3] = s3;
  sm[t][4] = q0; sm[t][5] = q1; sm[t][6] = q2; sm[t][7] = q3;
  __syncthreads();
  if (t < 64) {
#pragma unroll
    for (int j = 1; j < 4; ++j)
#pragma unroll
      for (int e = 0; e < 8; ++e) sm[t][e] += sm[t + 64 * j][e];
#pragma unroll
    for (int i = 0; i < 4; ++i) {
      part[((size_t)blockIdx.x * 256 + t * 4 + i) * 2 + 0] = sm[t][i];
      part[((size_t)blockIdx.x * 256 + t * 4 + i) * 2 + 1] = sm[t][4 + i];
    }
  }
}

// BN2 stats over out2T fp32 [65536][128]
__global__ __launch_bounds__(256) void bnstats2_k(const float* __restrict__ o2,
                                                  float* __restrict__ part) {
  int t = threadIdx.x, q = t & 31, ro = t >> 5;
  int r0 = blockIdx.x * 256;
  float s0 = 0, s1 = 0, s2 = 0, s3 = 0, q0 = 0, q1 = 0, q2 = 0, q3 = 0;
  for (int it = 0; it < 32; ++it) {
    size_t r = r0 + it * 8 + ro;
    float4 v = *(const float4*)&o2[r * 128 + q * 4];
    s0 += v.x; q0 += v.x * v.x;
    s1 += v.y; q1 += v.y * v.y;
    s2 += v.z; q2 += v.z * v.z;
    s3 += v.w; q3 += v.w * v.w;
  }
  __shared__ float sm[256][8];
  sm[t][0] = s0; sm[t][1] = s1; sm[t][2] = s2; sm[t][3] = s3;
  sm[t][4] = q0; sm[t][5] = q1; sm[t][6] = q2; sm[t][7] = q3;
  __syncthreads();
  if (t < 32) {
#pragma unroll
    for (int j = 1; j < 8; ++j)
#pragma unroll
      for (int e = 0; e < 8; ++e) sm[t][e] += sm[t + 32 * j][e];
#pragma unroll
    for (int i = 0; i < 4; ++i) {
      part[((size_t)blockIdx.x * 128 + t * 4 + i) * 2 + 0] = sm[t][i];
      part[((size_t)blockIdx.x * 128 + t * 4 + i) * 2 + 1] = sm[t][4 + i];
    }
  }
}

// fold partials -> per-channel a*x + c
template <int C>
__global__ __launch_bounds__(256) void bnfold_k(const float* __restrict__ part,
                                                const float* __restrict__ g,
                                                const float* __restrict__ be,
                                                float* __restrict__ A,
                                                float* __restrict__ Cc) {
  int c = threadIdx.x;
  if (c >= C) return;
  float s1 = 0.f, s2 = 0.f;
  for (int b = 0; b < 256; ++b) {
    s1 += part[((size_t)b * C + c) * 2 + 0];
    s2 += part[((size_t)b * C + c) * 2 + 1];
  }
  float mean = s1 * (1.f / 65536.f);
  float var = s2 * (1.f / 65536.f) - mean * mean;  // biased, as torch BN
  float a = g[c] * rsqrtf(var + 1e-5f);
  A[c] = a;
  Cc[c] = be[c] - mean * a;
}

// GEMM2 (MFMA) with fused BN1+ReLU on staging: out2T[n][c2] =
// sum_k w2[c2][k] relu(a1[k]*h1T[n][k]+c1[k]). K=256. grid (512).
__global__ __launch_bounds__(256) void gemm2_k(const unsigned short* __restrict__ h1T,
                                               const unsigned short* __restrict__ Wb,
                                               const float* __restrict__ A,
                                               const float* __restrict__ C,
                                               float* __restrict__ o2) {
  __shared__ unsigned short sW[128][40];
  __shared__ unsigned short sX[128][40];
  int t = threadIdx.x;
  int i0 = blockIdx.x * 128;
  int w = t >> 6, lane = t & 63;
  int wc = (w & 1) * 64, wn = (w >> 1) * 64;
  int l15 = lane & 15, g = lane >> 4;
  f32x4 acc[4][4];
#pragma unroll
  for (int a = 0; a < 4; ++a)
#pragma unroll
    for (int bq = 0; bq < 4; ++bq) acc[a][bq] = (f32x4)0.f;
  int sr = t & 127, sh = t >> 7;
  for (int kc = 0; kc < 8; ++kc) {
    int k0 = kc * 32;
    int kcol = k0 + sh * 16;
    __syncthreads();
    {
      const uint4* gw = (const uint4*)&Wb[(size_t)sr * 256 + kcol];
      uint4 v0 = gw[0], v1 = gw[1];
      *(uint4*)&sW[sr][sh * 16] = v0;
      *(uint4*)&sW[sr][sh * 16 + 8] = v1;
      const uint4* gx = (const uint4*)&h1T[(size_t)(i0 + sr) * 256 + kcol];
      uint4 x0 = gx[0], x1 = gx[1];
      unsigned rr[8] = {x0.x, x0.y, x0.z, x0.w, x1.x, x1.y, x1.z, x1.w};
      unsigned ww[8];
#pragma unroll
      for (int e = 0; e < 8; ++e) {  // BN1+relu fused while staging
        int ch = kcol + 2 * e;
        float f0 = bf2f((unsigned short)(rr[e] & 0xFFFFu));
        float f1 = bf2f((unsigned short)(rr[e] >> 16));
        f0 = fmaxf(fmaf(A[ch], f0, C[ch]), 0.f);
        f1 = fmaxf(fmaf(A[ch + 1], f1, C[ch + 1]), 0.f);
        ww[e] = (unsigned)f2bf(f0) | ((unsigned)f2bf(f1) << 16);
      }
      uint4 y0 = {ww[0], ww[1], ww[2], ww[3]};
      uint4 y1 = {ww[4], ww[5], ww[6], ww[7]};
      *(uint4*)&sX[sr][sh * 16] = y0;
      *(uint4*)&sX[sr][sh * 16 + 8] = y1;
    }
    __syncthreads();
    bf16x8 a[4], b[4];
#pragma unroll
    for (int tm = 0; tm < 4; ++tm)
      a[tm] = *(const bf16x8*)&sW[wc + tm * 16 + l15][g * 8];
#pragma unroll
    for (int tn = 0; tn < 4; ++tn)
      b[tn] = *(const bf16x8*)&sX[wn + tn * 16 + l15][g * 8];
#pragma unroll
    for (int tm = 0; tm < 4; ++tm)
#pragma unroll
      for (int tn = 0; tn < 4; ++tn)
        acc[tm][tn] = __builtin_amdgcn_mfma_f32_16x16x32_bf16(a[tm], b[tn], acc[tm][tn], 0, 0, 0);
  }
#pragma unroll
  for (int tm = 0; tm < 4; ++tm)
#pragma unroll
    for (int tn = 0; tn < 4; ++tn) {
      int c = wc + tm * 16 + g * 4;
      int n = i0 + wn + tn * 16 + l15;
      f32x4 v = acc[tm][tn];
      *(float4*)&o2[(size_t)n * 128 + c] = make_float4(v[0], v[1], v[2], v[3]);
    }
}

// final: out2T [i][128] + BN2 + relu -> d_out [B][128][16384] (transposed)
__global__ __launch_bounds__(256) void final_k(const float* __restrict__ o2,
                                               const float* __restrict__ A,
                                               const float* __restrict__ C,
                                               float* __restrict__ out) {
  __shared__ float tile[32][33];
  int b = blockIdx.z;
  int n0 = blockIdx.x * 32;
  int c0 = blockIdx.y * 32;
  int tx = threadIdx.x, ty = threadIdx.y;
  float a = A[c0 + tx], cc = C[c0 + tx];
  for (int r = ty; r < 32; r += 8) {
    float v = o2[(size_t)(b * 16384 + n0 + r) * 128 + c0 + tx];
    tile[r][tx] = fmaxf(fmaf(a, v, cc), 0.f);
  }
  __syncthreads();
  for (int r = ty; r < 32; r += 8)
    out[((size_t)(b * 128 + c0 + r)) * 16384 + n0 + tx] = tile[tx][r];
}

extern "C" void kernel_launch(void* const* d_in, const int* in_sizes, int n_in,
                              void* d_out, int out_size, void* d_ws, size_t ws_size,
                              hipStream_t stream) {
  const float* xyz1 = (const float*)d_in[0];
  const float* xyz2 = (const float*)d_in[1];
  const float* p1   = (const float*)d_in[2];
  const float* p2   = (const float*)d_in[3];
  const int*   idx1 = (const int*)d_in[4];
  const int*   idx2 = (const int*)d_in[5];
  const float* w1   = (const float*)d_in[6];
  // d_in[7]=b1, d_in[11]=b2: exactly absorbed by BN mean subtraction
  const float* g1   = (const float*)d_in[8];
  const float* be1  = (const float*)d_in[9];
  const float* w2   = (const float*)d_in[10];
  const float* g2   = (const float*)d_in[12];
  const float* be2  = (const float*)d_in[13];
  float* out = (float*)d_out;

  char* ws = (char*)d_ws;
  // idx3 | wgt | X 48MB | h1T 32MB (p2t bf16 8.4MB aliased, dead before
  // gemm1 writes) | o2 32MB (rec 12.6MB aliased, dead before gemm2 writes)
  // | w1b w2b part1 part2 pack 262KB params  => ~114MB
  int*            idx3 = (int*)(ws + 0x0);                      // 0.75MB
  float*          wgt  = (float*)(ws + 0xC0000);                // 0.75MB
  unsigned short* X    = (unsigned short*)(ws + 0x180000);      // 48MB
  unsigned short* h1T  = (unsigned short*)(ws + 0x3180000);     // 32MB
  unsigned short* p2t  = (unsigned short*)(ws + 0x3180000);     // alias h1T
  float*          o2   = (float*)(ws + 0x5180000);              // 32MB
  float*          rec  = (float*)(ws + 0x5180000);              // alias o2
  unsigned short* w1b  = (unsigned short*)(ws + 0x7180000);
  unsigned short* w2b  = (unsigned short*)(ws + 0x71B0000);
  float*          part1 = (float*)(ws + 0x71C0000);
  float*          part2 = (float*)(ws + 0x7240000);
  float4*         pack = (float4*)(ws + 0x7280000);             // 262KB
  float*          a1   = (float*)(ws + 0x72C8000);
  float*          c1   = a1 + 256;
  float*          a2   = c1 + 256;
  float*          c2   = a2 + 128;

  hipLaunchKernelGGL(transpose_k, dim3(128, 8, 4), dim3(32, 8), 0, stream, p2, p2t);
  hipLaunchKernelGGL(wcvtpack_k, dim3(576), dim3(256), 0, stream,
                     w1, w2, xyz2, idx1, idx2, w1b, w2b, pack);
  hipLaunchKernelGGL(p1t_k, dim3(512, 4, 4), dim3(32, 8), 0, stream, p1, X);
  hipLaunchKernelGGL(knn_k, dim3(2048), dim3(256), 0, stream,
                     xyz1, xyz2, idx1, idx2, pack, rec);
  hipLaunchKernelGGL(knnmerge_k, dim3(256), dim3(256), 0, stream, rec, idx3, wgt);
  hipLaunchKernelGGL(interp_k, dim3(512), dim3(256), 0, stream, p2t, idx3, wgt, X);
  hipLaunchKernelGGL(gemm1_k, dim3(512, 2), dim3(256), 0, stream, X, w1b, h1T);
  hipLaunchKernelGGL(bnstats1_k, dim3(256), dim3(256), 0, stream, h1T, part1);
  hipLaunchKernelGGL((bnfold_k<256>), dim3(1), dim3(256), 0, stream, part1, g1, be1, a1, c1);
  hipLaunchKernelGGL(gemm2_k, dim3(512), dim3(256), 0, stream, h1T, w2b, a1, c1, o2);
  hipLaunchKernelGGL(bnstats2_k, dim3(256), dim3(256), 0, stream, o2, part2);
  hipLaunchKernelGGL((bnfold_k<128>), dim3(1), dim3(256), 0, stream, part2, g2, be2, a2, c2);
  hipLaunchKernelGGL(final_k, dim3(512, 4, 4), dim3(32, 8), 0, stream, o2, a2, c2, out);
}

// Round 13
// 249.605 us; speedup vs baseline: 1.1192x; 1.0432x over previous
//
#include <hip/hip_runtime.h>
#include <hip/hip_bf16.h>

#define INF_F (__builtin_inff())

typedef __attribute__((ext_vector_type(8))) short bf16x8;
typedef __attribute__((ext_vector_type(4))) float f32x4;

__device__ __forceinline__ unsigned short f2bf(float f) {
  __hip_bfloat16 h = __float2bfloat16(f);
  return __builtin_bit_cast(unsigned short, h);
}
__device__ __forceinline__ float bf2f(unsigned short u) {
  return __uint_as_float((unsigned)u << 16);
}

// branchy sorted top-3 insert (scalar state only - R8 lesson: nothing
// address-taken). Strict < + ascending s = top_k lowest-index tie order.
#define TOP3_INS(d, sj, E0, E1, E2, J0, J1, J2)                      \
  {                                                                  \
    bool l0 = (d) < E0, l1 = (d) < E1;                               \
    E2 = l1 ? E1 : (d); J2 = l1 ? J1 : (sj);                         \
    E1 = l0 ? E0 : (l1 ? (d) : E1); J1 = l0 ? J0 : (l1 ? (sj) : J1); \
    E0 = l0 ? (d) : E0; J0 = l0 ? (sj) : J0;                         \
  }

// ---------------------------------------------------------------------------
// B=4, N=16384, S=4096, D1=128, D2=256, MLP=(256,128). M = B*N = 65536.
// X: [65536][384] bf16 (cols 0..127 = points1^T, 128..383 = interp)
// h1T: [65536][256] bf16 ; out2T: [65536][128] fp32.
// GEMMs: D[c][n] = W[c][k] * X[n][k] via mfma_f32_16x16x32_bf16.
// R13: 8 launches (was 13) - prep fused, BN stats fused into GEMM epilogues,
// knnmerge fused into interp.
// ---------------------------------------------------------------------------

// fused preprocessing: [0,4096) p2 transpose->bf16, [4096,12288) p1
// transpose->X, [12288,12864) weight cvt + source pack.
__global__ __launch_bounds__(256) void prep_k(const float* __restrict__ p2,
                                              const float* __restrict__ p1,
                                              const float* __restrict__ w1,
                                              const float* __restrict__ w2,
                                              const float* __restrict__ xyz2,
                                              const int* __restrict__ idx1,
                                              const int* __restrict__ idx2,
                                              unsigned short* __restrict__ p2t,
                                              unsigned short* __restrict__ X,
                                              unsigned short* __restrict__ w1b,
                                              unsigned short* __restrict__ w2b,
                                              float4* __restrict__ pack) {
  int id = blockIdx.x;
  int t = threadIdx.x;
  if (id < 4096) {  // p2 [B][256][4096] -> p2t [B][4096][256] bf16
    __shared__ float tile[32][33];
    int s0 = (id & 127) * 32;
    int k0 = ((id >> 7) & 7) * 32;
    int b = id >> 10;
    int tx = t & 31, ty = t >> 5;
    const float* src = p2 + ((size_t)b * 256 + k0) * 4096 + s0;
    for (int r = ty; r < 32; r += 8) tile[r][tx] = src[(size_t)r * 4096 + tx];
    __syncthreads();
    unsigned short* dst = p2t + ((size_t)b * 4096 + s0) * 256 + k0;
    for (int r = ty; r < 32; r += 8) dst[(size_t)r * 256 + tx] = f2bf(tile[tx][r]);
  } else if (id < 12288) {  // p1 [B][128][16384] -> X[.][0..127] bf16
    __shared__ float tile[32][33];
    int id2 = id - 4096;
    int n0 = (id2 & 511) * 32;
    int c0 = ((id2 >> 9) & 3) * 32;
    int b = id2 >> 11;
    int tx = t & 31, ty = t >> 5;
    const float* src = p1 + ((size_t)b * 128 + c0) * 16384 + n0;
    for (int r = ty; r < 32; r += 8) tile[r][tx] = src[(size_t)r * 16384 + tx];
    __syncthreads();
    for (int r = ty; r < 32; r += 8)
      X[((size_t)(b * 16384 + n0 + r)) * 384 + c0 + tx] = f2bf(tile[tx][r]);
  } else {  // weights cvt + pack
    int id3 = (id - 12288) * 256 + t;
    if (id3 < 98304) {
      w1b[id3] = f2bf(w1[id3]);
    } else if (id3 < 131072) {
      w2b[id3 - 98304] = f2bf(w2[id3 - 98304]);
    } else {
      int pid = id3 - 131072;
      int b = pid >> 12, s = pid & 4095;
      float x = xyz2[(b * 3 + 0) * 4096 + s];
      float y = xyz2[(b * 3 + 1) * 4096 + s];
      float z = xyz2[(b * 3 + 2) * 4096 + s];
      float w = fmaf(x, x, fmaf(y, y, z * z));
      int common = idx1[b * 16384];
      w = (idx2[b * 4096 + s] == common) ? w : 3e38f;  // invalid -> wgt 0
      pack[b * 4096 + s] = make_float4(x, y, z, w);
    }
  }
}

// 3-NN stage 1, scalar-pipe sources. 2048 blocks = 256 query-groups (256 q)
// x 8 S-slices (512 src). 1 query/thread, NO LDS, VGPR ~12. 8 blocks/CU ->
// 32 waves/CU (R12: occ 62%, VALUBusy 82%). Validity folded into pack's
// |p|^2. Exact per-thread fallback if id != common (never on this data).
__global__ __launch_bounds__(256) void knn_k(const float* __restrict__ xyz1,
                                             const float* __restrict__ xyz2,
                                             const int* __restrict__ idx1,
                                             const int* __restrict__ idx2,
                                             const float4* __restrict__ pack,
                                             float* __restrict__ rec) {
  int bid = blockIdx.x;
  int qg = bid >> 3, sl = bid & 7;
  int b = qg >> 6;               // 64 query-groups per batch
  int nloc = (qg & 63) << 8;     // 256 queries per group
  int t = threadIdx.x;
  int n = nloc + t;
  int q0i = b * 16384 + n;
  int common = idx1[b * 16384];
  int sbase = sl << 9;           // 512-source slice
  const float4* ps = pack + b * 4096 + sbase;
  float px = xyz1[(b * 3 + 0) * 16384 + n];
  float py = xyz1[(b * 3 + 1) * 16384 + n];
  float pz = xyz1[(b * 3 + 2) * 16384 + n];
  int myid = idx1[q0i];
  float pn = fmaf(px, px, fmaf(py, py, pz * pz));
  float qx = -2.f * px, qy = -2.f * py, qz = -2.f * pz;
  float e0 = INF_F, e1 = INF_F, e2 = INF_F;
  int j0 = 0, j1 = 0, j2 = 0;
#pragma unroll 8
  for (int s = 0; s < 512; ++s) {
    float4 p = ps[s];  // uniform addr -> scalar load (s_load_dwordx4/x16)
    float d = fmaf(qx, p.x, fmaf(qy, p.y, fmaf(qz, p.z, pn))) + p.w;
    if (__builtin_expect(d < e2, 0)) {  // 64 states/wave: genuinely skippable
      int sj = sbase + s;
      TOP3_INS(d, sj, e0, e1, e2, j0, j1, j2);
    }
  }
  if (__builtin_expect(myid != common, 0)) {  // exact general-idx fallback
    e0 = INF_F; e1 = INF_F; e2 = INF_F; j0 = 0; j1 = 0; j2 = 0;
    for (int s = 0; s < 512; ++s) {
      int gs = sbase + s;
      float x = xyz2[(b * 3 + 0) * 4096 + gs];
      float y = xyz2[(b * 3 + 1) * 4096 + gs];
      float z = xyz2[(b * 3 + 2) * 4096 + gs];
      float w = fmaf(x, x, fmaf(y, y, z * z));
      float d = fmaf(qx, x, fmaf(qy, y, fmaf(qz, z, pn))) + w;
      d = (idx2[b * 4096 + gs] == myid) ? d : INF_F;
      if (d < e2) TOP3_INS(d, gs, e0, e1, e2, j0, j1, j2);
    }
  }
  // rec layout [slice][query]: lane-consecutive 24B records => coalesced
  float* r = &rec[((size_t)sl * 65536 + q0i) * 6];
  r[0] = e0; r[1] = e1; r[2] = e2;
  ((int*)r)[3] = j0; ((int*)r)[4] = j1; ((int*)r)[5] = j2;
}

// fused: merge 8 S-slice records (lex (d,idx), ascending slice order = exact
// top_k ties) + inverse-distance weights + gather-interpolate into X.
// 512 blocks x 256 thr; block = 128 queries.
__global__ __launch_bounds__(256) void interpm_k(const float* __restrict__ rec,
                                                 const unsigned short* __restrict__ p2t,
                                                 unsigned short* __restrict__ X) {
  __shared__ int sId[128][3];
  __shared__ float sWt[128][3];
  int i0 = blockIdx.x * 128;
  int b = i0 >> 14;
  int t = threadIdx.x;
  if (t < 128) {
    int i = i0 + t;
    float e0, e1, e2;
    int j0, j1, j2;
    {
      const float* r = &rec[(size_t)i * 6];
      e0 = r[0]; e1 = r[1]; e2 = r[2];
      j0 = ((const int*)r)[3]; j1 = ((const int*)r)[4]; j2 = ((const int*)r)[5];
    }
#pragma unroll
    for (int c = 1; c < 8; ++c) {
      const float* r = &rec[((size_t)c * 65536 + i) * 6];
      const int* ir = (const int*)r;
#pragma unroll
      for (int w = 0; w < 3; ++w) {
        float d = r[w];
        int sj = ir[3 + w];
        bool l0 = (d < e0) || (d == e0 && sj < j0);
        bool l1 = (d < e1) || (d == e1 && sj < j1);
        bool l2 = (d < e2) || (d == e2 && sj < j2);
        e2 = l1 ? e1 : (l2 ? d : e2);
        j2 = l1 ? j1 : (l2 ? sj : j2);
        e1 = l0 ? e0 : (l1 ? d : e1);
        j1 = l0 ? j0 : (l1 ? sj : j1);
        e0 = l0 ? d : e0;
        j0 = l0 ? sj : j0;
      }
    }
    float r0 = 1.f / (e0 + 1e-8f);
    float r1 = 1.f / (e1 + 1e-8f);
    float r2 = 1.f / (e2 + 1e-8f);
    float rs = r0 + r1 + r2;
    sWt[t][0] = (e0 > 1e8f) ? 0.f : r0 / rs;  // ref: where(d3>BIG,0)+nan_to_num
    sWt[t][1] = (e1 > 1e8f) ? 0.f : r1 / rs;
    sWt[t][2] = (e2 > 1e8f) ? 0.f : r2 / rs;
    sId[t][0] = j0; sId[t][1] = j1; sId[t][2] = j2;
  }
  __syncthreads();
  int k = t;
  const unsigned short* base = p2t + (size_t)b * 4096 * 256;
#pragma unroll 2
  for (int ii = 0; ii < 128; ++ii) {
    int id0 = sId[ii][0], id1 = sId[ii][1], id2 = sId[ii][2];
    float w0 = sWt[ii][0], w1v = sWt[ii][1], w2v = sWt[ii][2];
    float v = w0 * bf2f(base[id0 * 256 + k]);
    v = fmaf(w1v, bf2f(base[id1 * 256 + k]), v);
    v = fmaf(w2v, bf2f(base[id2 * 256 + k]), v);
    X[(size_t)(i0 + ii) * 384 + 128 + k] = f2bf(v);
  }
}

// GEMM1 (MFMA): h1T[n][c] = sum_k w1[c][k] X[n][k]. 128x128 tile, BK=32,
// K=384. grid (512, 2). Epilogue: per-block BN1 partial stats (sum, sumsq
// per channel over the block's 128 n) from fp32 accumulators -> part1
// [512][256][2] (no atomics; bnfold sums 512). Channel of acc[tm][*][j] =
// c0 + wc + tm*16 + g*4 + j; threads sharing a channel differ in lane bits
// 0-3 (l15) and the wn wave bit -> shfl_xor reduce + LDS cross-wave.
__global__ __launch_bounds__(256) void gemm1_k(const unsigned short* __restrict__ X,
                                               const unsigned short* __restrict__ Wb,
                                               unsigned short* __restrict__ h1T,
                                               float* __restrict__ part1) {
  __shared__ unsigned short sW[128][40];
  __shared__ unsigned short sX[128][40];
  int t = threadIdx.x;
  int i0 = blockIdx.x * 128;
  int c0 = blockIdx.y * 128;
  int w = t >> 6, lane = t & 63;
  int wc = (w & 1) * 64, wni = w >> 1;
  int wn = wni * 64;
  int l15 = lane & 15, g = lane >> 4;
  f32x4 acc[4][4];
#pragma unroll
  for (int a = 0; a < 4; ++a)
#pragma unroll
    for (int bq = 0; bq < 4; ++bq) acc[a][bq] = (f32x4)0.f;
  int sr = t & 127, sh = t >> 7;
  for (int kc = 0; kc < 12; ++kc) {
    int k0 = kc * 32;
    __syncthreads();
    {
      const uint4* gw = (const uint4*)&Wb[(size_t)(c0 + sr) * 384 + k0 + sh * 16];
      uint4 v0 = gw[0], v1 = gw[1];
      *(uint4*)&sW[sr][sh * 16] = v0;
      *(uint4*)&sW[sr][sh * 16 + 8] = v1;
      const uint4* gx = (const uint4*)&X[(size_t)(i0 + sr) * 384 + k0 + sh * 16];
      uint4 x0 = gx[0], x1 = gx[1];
      *(uint4*)&sX[sr][sh * 16] = x0;
      *(uint4*)&sX[sr][sh * 16 + 8] = x1;
    }
    __syncthreads();
    bf16x8 a[4], b[4];
#pragma unroll
    for (int tm = 0; tm < 4; ++tm)
      a[tm] = *(const bf16x8*)&sW[wc + tm * 16 + l15][g * 8];
#pragma unroll
    for (int tn = 0; tn < 4; ++tn)
      b[tn] = *(const bf16x8*)&sX[wn + tn * 16 + l15][g * 8];
#pragma unroll
    for (int tm = 0; tm < 4; ++tm)
#pragma unroll
      for (int tn = 0; tn < 4; ++tn)
        acc[tm][tn] = __builtin_amdgcn_mfma_f32_16x16x32_bf16(a[tm], b[tn], acc[tm][tn], 0, 0, 0);
  }
#pragma unroll
  for (int tm = 0; tm < 4; ++tm)
#pragma unroll
    for (int tn = 0; tn < 4; ++tn) {
      int c = c0 + wc + tm * 16 + g * 4;
      int n = i0 + wn + tn * 16 + l15;
      f32x4 v = acc[tm][tn];
      ushort4 o;
      o.x = f2bf(v[0]); o.y = f2bf(v[1]); o.z = f2bf(v[2]); o.w = f2bf(v[3]);
      *(ushort4*)&h1T[(size_t)n * 256 + c] = o;
    }
  // --- fused BN1 partial stats (fp32 acc = closer to fp32 ref than bf16) ---
  float s_[4][4], q_[4][4];
#pragma unroll
  for (int tm = 0; tm < 4; ++tm)
#pragma unroll
    for (int j = 0; j < 4; ++j) {
      float s = 0.f, q = 0.f;
#pragma unroll
      for (int tn = 0; tn < 4; ++tn) {
        float v = acc[tm][tn][j];
        s += v; q = fmaf(v, v, q);
      }
      s_[tm][j] = s; q_[tm][j] = q;
    }
#pragma unroll
  for (int mask = 1; mask < 16; mask <<= 1)
#pragma unroll
    for (int tm = 0; tm < 4; ++tm)
#pragma unroll
      for (int j = 0; j < 4; ++j) {
        s_[tm][j] += __shfl_xor(s_[tm][j], mask);
        q_[tm][j] += __shfl_xor(q_[tm][j], mask);
      }
  __syncthreads();                 // LDS reuse: sW as float red[2][128][2]
  float* red = (float*)&sW[0][0];
  if (l15 == 0) {
#pragma unroll
    for (int tm = 0; tm < 4; ++tm)
#pragma unroll
      for (int j = 0; j < 4; ++j) {
        int cl = wc + tm * 16 + g * 4 + j;
        red[(wni * 128 + cl) * 2 + 0] = s_[tm][j];
        red[(wni * 128 + cl) * 2 + 1] = q_[tm][j];
      }
  }
  __syncthreads();
  if (t < 256) {
    int cl = t >> 1, st = t & 1;
    float v = red[(0 * 128 + cl) * 2 + st] + red[(1 * 128 + cl) * 2 + st];
    part1[((size_t)blockIdx.x * 256 + c0 + cl) * 2 + st] = v;
  }
}

// fold per-block partials -> per-channel a*x + c. NB blocks per channel.
template <int C, int NB>
__global__ __launch_bounds__(256) void bnfold_k(const float* __restrict__ part,
                                                const float* __restrict__ g,
                                                const float* __restrict__ be,
                                                float* __restrict__ A,
                                                float* __restrict__ Cc) {
  int c = threadIdx.x;
  if (c >= C) return;
  float s1 = 0.f, s2 = 0.f;
  for (int b = 0; b < NB; ++b) {
    s1 += part[((size_t)b * C + c) * 2 + 0];
    s2 += part[((size_t)b * C + c) * 2 + 1];
  }
  float mean = s1 * (1.f / 65536.f);
  float var = s2 * (1.f / 65536.f) - mean * mean;  // biased, as torch BN
  float a = g[c] * rsqrtf(var + 1e-5f);
  A[c] = a;
  Cc[c] = be[c] - mean * a;
}

// GEMM2 (MFMA) with fused BN1+ReLU on staging + fused BN2 partial stats.
// out2T[n][c2] = sum_k w2[c2][k] relu(a1[k]*h1T[n][k]+c1[k]). K=256. grid 512.
__global__ __launch_bounds__(256) void gemm2_k(const unsigned short* __restrict__ h1T,
                                               const unsigned short* __restrict__ Wb,
                                               const float* __restrict__ A,
                                               const float* __restrict__ C,
                                               float* __restrict__ o2,
                                               float* __restrict__ part2) {
  __shared__ unsigned short sW[128][40];
  __shared__ unsigned short sX[128][40];
  int t = threadIdx.x;
  int i0 = blockIdx.x * 128;
  int w = t >> 6, lane = t & 63;
  int wc = (w & 1) * 64, wni = w >> 1;
  int wn = wni * 64;
  int l15 = lane & 15, g = lane >> 4;
  f32x4 acc[4][4];
#pragma unroll
  for (int a = 0; a < 4; ++a)
#pragma unroll
    for (int bq = 0; bq < 4; ++bq) acc[a][bq] = (f32x4)0.f;
  int sr = t & 127, sh = t >> 7;
  for (int kc = 0; kc < 8; ++kc) {
    int k0 = kc * 32;
    int kcol = k0 + sh * 16;
    __syncthreads();
    {
      const uint4* gw = (const uint4*)&Wb[(size_t)sr * 256 + kcol];
      uint4 v0 = gw[0], v1 = gw[1];
      *(uint4*)&sW[sr][sh * 16] = v0;
      *(uint4*)&sW[sr][sh * 16 + 8] = v1;
      const uint4* gx = (const uint4*)&h1T[(size_t)(i0 + sr) * 256 + kcol];
      uint4 x0 = gx[0], x1 = gx[1];
      unsigned rr[8] = {x0.x, x0.y, x0.z, x0.w, x1.x, x1.y, x1.z, x1.w};
      unsigned ww[8];
#pragma unroll
      for (int e = 0; e < 8; ++e) {  // BN1+relu fused while staging
        int ch = kcol + 2 * e;
        float f0 = bf2f((unsigned short)(rr[e] & 0xFFFFu));
        float f1 = bf2f((unsigned short)(rr[e] >> 16));
        f0 = fmaxf(fmaf(A[ch], f0, C[ch]), 0.f);
        f1 = fmaxf(fmaf(A[ch + 1], f1, C[ch + 1]), 0.f);
        ww[e] = (unsigned)f2bf(f0) | ((unsigned)f2bf(f1) << 16);
      }
      uint4 y0 = {ww[0], ww[1], ww[2], ww[3]};
      uint4 y1 = {ww[4], ww[5], ww[6], ww[7]};
      *(uint4*)&sX[sr][sh * 16] = y0;
      *(uint4*)&sX[sr][sh * 16 + 8] = y1;
    }
    __syncthreads();
    bf16x8 a[4], b[4];
#pragma unroll
    for (int tm = 0; tm < 4; ++tm)
      a[tm] = *(const bf16x8*)&sW[wc + tm * 16 + l15][g * 8];
#pragma unroll
    for (int tn = 0; tn < 4; ++tn)
      b[tn] = *(const bf16x8*)&sX[wn + tn * 16 + l15][g * 8];
#pragma unroll
    for (int tm = 0; tm < 4; ++tm)
#pragma unroll
      for (int tn = 0; tn < 4; ++tn)
        acc[tm][tn] = __builtin_amdgcn_mfma_f32_16x16x32_bf16(a[tm], b[tn], acc[tm][tn], 0, 0, 0);
  }
#pragma unroll
  for (int tm = 0; tm < 4; ++tm)
#pragma unroll
    for (int tn = 0; tn < 4; ++tn) {
      int c = wc + tm * 16 + g * 4;
      int n = i0 + wn + tn * 16 + l15;
      f32x4 v = acc[tm][tn];
      *(float4*)&o2[(size_t)n * 128 + c] = make_float4(v[0], v[1], v[2], v[3]);
    }
  // --- fused BN2 partial stats ---
  float s_[4][4], q_[4][4];
#pragma unroll
  for (int tm = 0; tm < 4; ++tm)
#pragma unroll
    for (int j = 0; j < 4; ++j) {
      float s = 0.f, q = 0.f;
#pragma unroll
      for (int tn = 0; tn < 4; ++tn) {
        float v = acc[tm][tn][j];
        s += v; q = fmaf(v, v, q);
      }
      s_[tm][j] = s; q_[tm][j] = q;
    }
#pragma unroll
  for (int mask = 1; mask < 16; mask <<= 1)
#pragma unroll
    for (int tm = 0; tm < 4; ++tm)
#pragma unroll
      for (int j = 0; j < 4; ++j) {
        s_[tm][j] += __shfl_xor(s_[tm][j], mask);
        q_[tm][j] += __shfl_xor(q_[tm][j], mask);
      }
  __syncthreads();
  float* red = (float*)&sW[0][0];  // [2][128][2]
  if (l15 == 0) {
#pragma unroll
    for (int tm = 0; tm < 4; ++tm)
#pragma unroll
      for (int j = 0; j < 4; ++j) {
        int cl = wc + tm * 16 + g * 4 + j;
        red[(wni * 128 + cl) * 2 + 0] = s_[tm][j];
        red[(wni * 128 + cl) * 2 + 1] = q_[tm][j];
      }
  }
  __syncthreads();
  if (t < 256) {
    int cl = t >> 1, st = t & 1;
    float v = red[(0 * 128 + cl) * 2 + st] + red[(1 * 128 + cl) * 2 + st];
    part2[((size_t)blockIdx.x * 128 + cl) * 2 + st] = v;
  }
}

// final: out2T [i][128] + BN2 + relu -> d_out [B][128][16384] (transposed)
__global__ __launch_bounds__(256) void final_k(const float* __restrict__ o2,
                                               const float* __restrict__ A,
                                               const float* __restrict__ C,
                                               float* __restrict__ out) {
  __shared__ float tile[32][33];
  int b = blockIdx.z;
  int n0 = blockIdx.x * 32;
  int c0 = blockIdx.y * 32;
  int tx = threadIdx.x, ty = threadIdx.y;
  float a = A[c0 + tx], cc = C[c0 + tx];
  for (int r = ty; r < 32; r += 8) {
    float v = o2[(size_t)(b * 16384 + n0 + r) * 128 + c0 + tx];
    tile[r][tx] = fmaxf(fmaf(a, v, cc), 0.f);
  }
  __syncthreads();
  for (int r = ty; r < 32; r += 8)
    out[((size_t)(b * 128 + c0 + r)) * 16384 + n0 + tx] = tile[tx][r];
}

extern "C" void kernel_launch(void* const* d_in, const int* in_sizes, int n_in,
                              void* d_out, int out_size, void* d_ws, size_t ws_size,
                              hipStream_t stream) {
  const float* xyz1 = (const float*)d_in[0];
  const float* xyz2 = (const float*)d_in[1];
  const float* p1   = (const float*)d_in[2];
  const float* p2   = (const float*)d_in[3];
  const int*   idx1 = (const int*)d_in[4];
  const int*   idx2 = (const int*)d_in[5];
  const float* w1   = (const float*)d_in[6];
  // d_in[7]=b1, d_in[11]=b2: exactly absorbed by BN mean subtraction
  const float* g1   = (const float*)d_in[8];
  const float* be1  = (const float*)d_in[9];
  const float* w2   = (const float*)d_in[10];
  const float* g2   = (const float*)d_in[12];
  const float* be2  = (const float*)d_in[13];
  float* out = (float*)d_out;

  char* ws = (char*)d_ws;
  // X 48MB | h1T 32MB (p2t bf16 8.4MB aliased: dead before gemm1 writes)
  // | o2 32MB (rec 12.6MB aliased: dead before gemm2 writes) | w1b w2b
  // | part1 1MB | part2 0.5MB | pack 262KB | params  => ~114MB
  unsigned short* X    = (unsigned short*)(ws + 0x180000);      // 48MB
  unsigned short* h1T  = (unsigned short*)(ws + 0x3180000);     // 32MB
  unsigned short* p2t  = (unsigned short*)(ws + 0x3180000);     // alias h1T
  float*          o2   = (float*)(ws + 0x5180000);              // 32MB
  float*          rec  = (float*)(ws + 0x5180000);              // alias o2
  unsigned short* w1b  = (unsigned short*)(ws + 0x7180000);
  unsigned short* w2b  = (unsigned short*)(ws + 0x71B0000);
  float*          part1 = (float*)(ws + 0x71C0000);             // 1MB
  float*          part2 = (float*)(ws + 0x72C0000);             // 0.5MB
  float4*         pack = (float4*)(ws + 0x7340000);             // 262KB
  float*          a1   = (float*)(ws + 0x7388000);
  float*          c1   = a1 + 256;
  float*          a2   = c1 + 256;
  float*          c2   = a2 + 128;

  hipLaunchKernelGGL(prep_k, dim3(12864), dim3(256), 0, stream,
                     p2, p1, w1, w2, xyz2, idx1, idx2, p2t, X, w1b, w2b, pack);
  hipLaunchKernelGGL(knn_k, dim3(2048), dim3(256), 0, stream,
                     xyz1, xyz2, idx1, idx2, pack, rec);
  hipLaunchKernelGGL(interpm_k, dim3(512), dim3(256), 0, stream, rec, p2t, X);
  hipLaunchKernelGGL(gemm1_k, dim3(512, 2), dim3(256), 0, stream, X, w1b, h1T, part1);
  hipLaunchKernelGGL((bnfold_k<256, 512>), dim3(1), dim3(256), 0, stream,
                     part1, g1, be1, a1, c1);
  hipLaunchKernelGGL(gemm2_k, dim3(512), dim3(256), 0, stream,
                     h1T, w2b, a1, c1, o2, part2);
  hipLaunchKernelGGL((bnfold_k<128, 512>), dim3(1), dim3(256), 0, stream,
                     part2, g2, be2, a2, c2);
  hipLaunchKernelGGL(final_k, dim3(512, 4, 4), dim3(32, 8), 0, stream, o2, a2, c2, out);
}

// Round 14
// 233.691 us; speedup vs baseline: 1.1954x; 1.0681x over previous
//
#include <hip/hip_runtime.h>
#include <hip/hip_bf16.h>

#define INF_F (__builtin_inff())

typedef __attribute__((ext_vector_type(8))) short bf16x8;
typedef __attribute__((ext_vector_type(4))) float f32x4;

__device__ __forceinline__ unsigned short f2bf(float f) {
  __hip_bfloat16 h = __float2bfloat16(f);
  return __builtin_bit_cast(unsigned short, h);
}
__device__ __forceinline__ float bf2f(unsigned short u) {
  return __uint_as_float((unsigned)u << 16);
}

// branchy sorted top-3 insert (scalar state only - R8 lesson: nothing
// address-taken). Strict < + ascending s = top_k lowest-index tie order.
#define TOP3_INS(d, sj, E0, E1, E2, J0, J1, J2)                      \
  {                                                                  \
    bool l0 = (d) < E0, l1 = (d) < E1;                               \
    E2 = l1 ? E1 : (d); J2 = l1 ? J1 : (sj);                         \
    E1 = l0 ? E0 : (l1 ? (d) : E1); J1 = l0 ? J0 : (l1 ? (sj) : J1); \
    E0 = l0 ? (d) : E0; J0 = l0 ? (sj) : J0;                         \
  }

// ---------------------------------------------------------------------------
// B=4, N=16384, S=4096, D1=128, D2=256, MLP=(256,128). M = B*N = 65536.
// X: [65536][384] bf16 ; h1T: [65536][256] bf16 ; o2: [65536][128] bf16.
// GEMMs: D[c][n] = W[c][k] * X[n][k] via mfma_f32_16x16x32_bf16.
// R14: 6 launches. BN folding via fp32 atomicAdd into stats[768]
// (stats1=[256][2], stats2=[128][2]); consumer kernels fold in prologue.
// ---------------------------------------------------------------------------

// fused preprocessing: [0,4096) p2 transpose->bf16, [4096,12288) p1
// transpose->X, [12288,12864) weight cvt + source pack, [12864] zero stats.
__global__ __launch_bounds__(256) void prep_k(const float* __restrict__ p2,
                                              const float* __restrict__ p1,
                                              const float* __restrict__ w1,
                                              const float* __restrict__ w2,
                                              const float* __restrict__ xyz2,
                                              const int* __restrict__ idx1,
                                              const int* __restrict__ idx2,
                                              unsigned short* __restrict__ p2t,
                                              unsigned short* __restrict__ X,
                                              unsigned short* __restrict__ w1b,
                                              unsigned short* __restrict__ w2b,
                                              float4* __restrict__ pack,
                                              float* __restrict__ stats) {
  int id = blockIdx.x;
  int t = threadIdx.x;
  if (id < 4096) {  // p2 [B][256][4096] -> p2t [B][4096][256] bf16
    __shared__ float tile[32][33];
    int s0 = (id & 127) * 32;
    int k0 = ((id >> 7) & 7) * 32;
    int b = id >> 10;
    int tx = t & 31, ty = t >> 5;
    const float* src = p2 + ((size_t)b * 256 + k0) * 4096 + s0;
    for (int r = ty; r < 32; r += 8) tile[r][tx] = src[(size_t)r * 4096 + tx];
    __syncthreads();
    unsigned short* dst = p2t + ((size_t)b * 4096 + s0) * 256 + k0;
    for (int r = ty; r < 32; r += 8) dst[(size_t)r * 256 + tx] = f2bf(tile[tx][r]);
  } else if (id < 12288) {  // p1 [B][128][16384] -> X[.][0..127] bf16
    __shared__ float tile[32][33];
    int id2 = id - 4096;
    int n0 = (id2 & 511) * 32;
    int c0 = ((id2 >> 9) & 3) * 32;
    int b = id2 >> 11;
    int tx = t & 31, ty = t >> 5;
    const float* src = p1 + ((size_t)b * 128 + c0) * 16384 + n0;
    for (int r = ty; r < 32; r += 8) tile[r][tx] = src[(size_t)r * 16384 + tx];
    __syncthreads();
    for (int r = ty; r < 32; r += 8)
      X[((size_t)(b * 16384 + n0 + r)) * 384 + c0 + tx] = f2bf(tile[tx][r]);
  } else if (id < 12864) {  // weights cvt + pack
    int id3 = (id - 12288) * 256 + t;
    if (id3 < 98304) {
      w1b[id3] = f2bf(w1[id3]);
    } else if (id3 < 131072) {
      w2b[id3 - 98304] = f2bf(w2[id3 - 98304]);
    } else {
      int pid = id3 - 131072;
      int b = pid >> 12, s = pid & 4095;
      float x = xyz2[(b * 3 + 0) * 4096 + s];
      float y = xyz2[(b * 3 + 1) * 4096 + s];
      float z = xyz2[(b * 3 + 2) * 4096 + s];
      float w = fmaf(x, x, fmaf(y, y, z * z));
      int common = idx1[b * 16384];
      w = (idx2[b * 4096 + s] == common) ? w : 3e38f;  // invalid -> wgt 0
      pack[b * 4096 + s] = make_float4(x, y, z, w);
    }
  } else {  // zero BN stats accumulators (atomicAdd targets)
    for (int i = t; i < 768; i += 256) stats[i] = 0.f;
  }
}

// 3-NN stage 1, scalar-pipe sources. 2048 blocks = 256 query-groups (256 q)
// x 8 S-slices (512 src). 1 query/thread, NO LDS, VGPR ~12. 8 blocks/CU ->
// 32 waves/CU (R12: occ 62%, VALUBusy 82%). Validity folded into pack's
// |p|^2. Exact per-thread fallback if id != common (never on this data).
__global__ __launch_bounds__(256) void knn_k(const float* __restrict__ xyz1,
                                             const float* __restrict__ xyz2,
                                             const int* __restrict__ idx1,
                                             const int* __restrict__ idx2,
                                             const float4* __restrict__ pack,
                                             float* __restrict__ rec) {
  int bid = blockIdx.x;
  int qg = bid >> 3, sl = bid & 7;
  int b = qg >> 6;               // 64 query-groups per batch
  int nloc = (qg & 63) << 8;     // 256 queries per group
  int t = threadIdx.x;
  int n = nloc + t;
  int q0i = b * 16384 + n;
  int common = idx1[b * 16384];
  int sbase = sl << 9;           // 512-source slice
  const float4* ps = pack + b * 4096 + sbase;
  float px = xyz1[(b * 3 + 0) * 16384 + n];
  float py = xyz1[(b * 3 + 1) * 16384 + n];
  float pz = xyz1[(b * 3 + 2) * 16384 + n];
  int myid = idx1[q0i];
  float pn = fmaf(px, px, fmaf(py, py, pz * pz));
  float qx = -2.f * px, qy = -2.f * py, qz = -2.f * pz;
  float e0 = INF_F, e1 = INF_F, e2 = INF_F;
  int j0 = 0, j1 = 0, j2 = 0;
#pragma unroll 8
  for (int s = 0; s < 512; ++s) {
    float4 p = ps[s];  // uniform addr -> scalar load (s_load_dwordx4/x16)
    float d = fmaf(qx, p.x, fmaf(qy, p.y, fmaf(qz, p.z, pn))) + p.w;
    if (__builtin_expect(d < e2, 0)) {  // 64 states/wave: genuinely skippable
      int sj = sbase + s;
      TOP3_INS(d, sj, e0, e1, e2, j0, j1, j2);
    }
  }
  if (__builtin_expect(myid != common, 0)) {  // exact general-idx fallback
    e0 = INF_F; e1 = INF_F; e2 = INF_F; j0 = 0; j1 = 0; j2 = 0;
    for (int s = 0; s < 512; ++s) {
      int gs = sbase + s;
      float x = xyz2[(b * 3 + 0) * 4096 + gs];
      float y = xyz2[(b * 3 + 1) * 4096 + gs];
      float z = xyz2[(b * 3 + 2) * 4096 + gs];
      float w = fmaf(x, x, fmaf(y, y, z * z));
      float d = fmaf(qx, x, fmaf(qy, y, fmaf(qz, z, pn))) + w;
      d = (idx2[b * 4096 + gs] == myid) ? d : INF_F;
      if (d < e2) TOP3_INS(d, gs, e0, e1, e2, j0, j1, j2);
    }
  }
  // rec layout [slice][query]: lane-consecutive 24B records => coalesced
  float* r = &rec[((size_t)sl * 65536 + q0i) * 6];
  r[0] = e0; r[1] = e1; r[2] = e2;
  ((int*)r)[3] = j0; ((int*)r)[4] = j1; ((int*)r)[5] = j2;
}

// fused: merge 8 S-slice records (lex (d,idx), ascending slice order = exact
// top_k ties) + inverse-distance weights + gather-interpolate into X.
// 512 blocks x 256 thr; block = 128 queries.
__global__ __launch_bounds__(256) void interpm_k(const float* __restrict__ rec,
                                                 const unsigned short* __restrict__ p2t,
                                                 unsigned short* __restrict__ X) {
  __shared__ int sId[128][3];
  __shared__ float sWt[128][3];
  int i0 = blockIdx.x * 128;
  int b = i0 >> 14;
  int t = threadIdx.x;
  if (t < 128) {
    int i = i0 + t;
    float e0, e1, e2;
    int j0, j1, j2;
    {
      const float* r = &rec[(size_t)i * 6];
      e0 = r[0]; e1 = r[1]; e2 = r[2];
      j0 = ((const int*)r)[3]; j1 = ((const int*)r)[4]; j2 = ((const int*)r)[5];
    }
#pragma unroll
    for (int c = 1; c < 8; ++c) {
      const float* r = &rec[((size_t)c * 65536 + i) * 6];
      const int* ir = (const int*)r;
#pragma unroll
      for (int w = 0; w < 3; ++w) {
        float d = r[w];
        int sj = ir[3 + w];
        bool l0 = (d < e0) || (d == e0 && sj < j0);
        bool l1 = (d < e1) || (d == e1 && sj < j1);
        bool l2 = (d < e2) || (d == e2 && sj < j2);
        e2 = l1 ? e1 : (l2 ? d : e2);
        j2 = l1 ? j1 : (l2 ? sj : j2);
        e1 = l0 ? e0 : (l1 ? d : e1);
        j1 = l0 ? j0 : (l1 ? sj : j1);
        e0 = l0 ? d : e0;
        j0 = l0 ? sj : j0;
      }
    }
    float r0 = 1.f / (e0 + 1e-8f);
    float r1 = 1.f / (e1 + 1e-8f);
    float r2 = 1.f / (e2 + 1e-8f);
    float rs = r0 + r1 + r2;
    sWt[t][0] = (e0 > 1e8f) ? 0.f : r0 / rs;  // ref: where(d3>BIG,0)+nan_to_num
    sWt[t][1] = (e1 > 1e8f) ? 0.f : r1 / rs;
    sWt[t][2] = (e2 > 1e8f) ? 0.f : r2 / rs;
    sId[t][0] = j0; sId[t][1] = j1; sId[t][2] = j2;
  }
  __syncthreads();
  int k = t;
  const unsigned short* base = p2t + (size_t)b * 4096 * 256;
#pragma unroll 2
  for (int ii = 0; ii < 128; ++ii) {
    int id0 = sId[ii][0], id1 = sId[ii][1], id2 = sId[ii][2];
    float w0 = sWt[ii][0], w1v = sWt[ii][1], w2v = sWt[ii][2];
    float v = w0 * bf2f(base[id0 * 256 + k]);
    v = fmaf(w1v, bf2f(base[id1 * 256 + k]), v);
    v = fmaf(w2v, bf2f(base[id2 * 256 + k]), v);
    X[(size_t)(i0 + ii) * 384 + 128 + k] = f2bf(v);
  }
}

// GEMM1 (MFMA): h1T[n][c] = sum_k w1[c][k] X[n][k]. 128x128 tile, BK=32,
// K=384. grid (512, 2). Epilogue: per-block BN1 stats (sum,sumsq per
// channel over block's 128 n) from fp32 acc -> atomicAdd into stats1[256][2].
// Channel of acc[tm][*][j] = c0+wc+tm*16+g*4+j; threads sharing a channel
// differ in l15 bits + wn wave bit -> shfl_xor reduce + LDS cross-wave.
__global__ __launch_bounds__(256) void gemm1_k(const unsigned short* __restrict__ X,
                                               const unsigned short* __restrict__ Wb,
                                               unsigned short* __restrict__ h1T,
                                               float* __restrict__ stats1) {
  __shared__ unsigned short sW[128][40];
  __shared__ unsigned short sX[128][40];
  int t = threadIdx.x;
  int i0 = blockIdx.x * 128;
  int c0 = blockIdx.y * 128;
  int w = t >> 6, lane = t & 63;
  int wc = (w & 1) * 64, wni = w >> 1;
  int wn = wni * 64;
  int l15 = lane & 15, g = lane >> 4;
  f32x4 acc[4][4];
#pragma unroll
  for (int a = 0; a < 4; ++a)
#pragma unroll
    for (int bq = 0; bq < 4; ++bq) acc[a][bq] = (f32x4)0.f;
  int sr = t & 127, sh = t >> 7;
  for (int kc = 0; kc < 12; ++kc) {
    int k0 = kc * 32;
    __syncthreads();
    {
      const uint4* gw = (const uint4*)&Wb[(size_t)(c0 + sr) * 384 + k0 + sh * 16];
      uint4 v0 = gw[0], v1 = gw[1];
      *(uint4*)&sW[sr][sh * 16] = v0;
      *(uint4*)&sW[sr][sh * 16 + 8] = v1;
      const uint4* gx = (const uint4*)&X[(size_t)(i0 + sr) * 384 + k0 + sh * 16];
      uint4 x0 = gx[0], x1 = gx[1];
      *(uint4*)&sX[sr][sh * 16] = x0;
      *(uint4*)&sX[sr][sh * 16 + 8] = x1;
    }
    __syncthreads();
    bf16x8 a[4], b[4];
#pragma unroll
    for (int tm = 0; tm < 4; ++tm)
      a[tm] = *(const bf16x8*)&sW[wc + tm * 16 + l15][g * 8];
#pragma unroll
    for (int tn = 0; tn < 4; ++tn)
      b[tn] = *(const bf16x8*)&sX[wn + tn * 16 + l15][g * 8];
#pragma unroll
    for (int tm = 0; tm < 4; ++tm)
#pragma unroll
      for (int tn = 0; tn < 4; ++tn)
        acc[tm][tn] = __builtin_amdgcn_mfma_f32_16x16x32_bf16(a[tm], b[tn], acc[tm][tn], 0, 0, 0);
  }
#pragma unroll
  for (int tm = 0; tm < 4; ++tm)
#pragma unroll
    for (int tn = 0; tn < 4; ++tn) {
      int c = c0 + wc + tm * 16 + g * 4;
      int n = i0 + wn + tn * 16 + l15;
      f32x4 v = acc[tm][tn];
      ushort4 o;
      o.x = f2bf(v[0]); o.y = f2bf(v[1]); o.z = f2bf(v[2]); o.w = f2bf(v[3]);
      *(ushort4*)&h1T[(size_t)n * 256 + c] = o;
    }
  // --- fused BN1 stats (fp32 acc) -> atomicAdd ---
  float s_[4][4], q_[4][4];
#pragma unroll
  for (int tm = 0; tm < 4; ++tm)
#pragma unroll
    for (int j = 0; j < 4; ++j) {
      float s = 0.f, q = 0.f;
#pragma unroll
      for (int tn = 0; tn < 4; ++tn) {
        float v = acc[tm][tn][j];
        s += v; q = fmaf(v, v, q);
      }
      s_[tm][j] = s; q_[tm][j] = q;
    }
#pragma unroll
  for (int mask = 1; mask < 16; mask <<= 1)
#pragma unroll
    for (int tm = 0; tm < 4; ++tm)
#pragma unroll
      for (int j = 0; j < 4; ++j) {
        s_[tm][j] += __shfl_xor(s_[tm][j], mask);
        q_[tm][j] += __shfl_xor(q_[tm][j], mask);
      }
  __syncthreads();                 // LDS reuse: sW as float red[2][128][2]
  float* red = (float*)&sW[0][0];
  if (l15 == 0) {
#pragma unroll
    for (int tm = 0; tm < 4; ++tm)
#pragma unroll
      for (int j = 0; j < 4; ++j) {
        int cl = wc + tm * 16 + g * 4 + j;
        red[(wni * 128 + cl) * 2 + 0] = s_[tm][j];
        red[(wni * 128 + cl) * 2 + 1] = q_[tm][j];
      }
  }
  __syncthreads();
  {
    int cl = t >> 1, st = t & 1;
    float v = red[(0 * 128 + cl) * 2 + st] + red[(1 * 128 + cl) * 2 + st];
    atomicAdd(&stats1[((c0 + cl) << 1) + st], v);
  }
}

// GEMM2 (MFMA). Prologue: fold stats1 -> per-channel BN1 a/c in LDS.
// Staging: BN1+relu fused. Epilogue: bf16 o2 write + BN2 stats atomicAdd.
__global__ __launch_bounds__(256) void gemm2_k(const unsigned short* __restrict__ h1T,
                                               const unsigned short* __restrict__ Wb,
                                               const float* __restrict__ stats1,
                                               const float* __restrict__ g1,
                                               const float* __restrict__ be1,
                                               unsigned short* __restrict__ o2,
                                               float* __restrict__ stats2) {
  __shared__ unsigned short sW[128][40];
  __shared__ unsigned short sX[128][40];
  __shared__ float sA1[256], sC1[256];
  int t = threadIdx.x;
  int i0 = blockIdx.x * 128;
  int w = t >> 6, lane = t & 63;
  int wc = (w & 1) * 64, wni = w >> 1;
  int wn = wni * 64;
  int l15 = lane & 15, g = lane >> 4;
  {  // fold BN1 (redundant per block; 256 ch, trivial)
    float s1v = stats1[t * 2 + 0], s2v = stats1[t * 2 + 1];
    float mean = s1v * (1.f / 65536.f);
    float var = s2v * (1.f / 65536.f) - mean * mean;  // biased, as torch BN
    float a = g1[t] * rsqrtf(var + 1e-5f);
    sA1[t] = a;
    sC1[t] = be1[t] - mean * a;
  }
  f32x4 acc[4][4];
#pragma unroll
  for (int a = 0; a < 4; ++a)
#pragma unroll
    for (int bq = 0; bq < 4; ++bq) acc[a][bq] = (f32x4)0.f;
  int sr = t & 127, sh = t >> 7;
  for (int kc = 0; kc < 8; ++kc) {
    int k0 = kc * 32;
    int kcol = k0 + sh * 16;
    __syncthreads();  // also covers prologue->staging dependency at kc=0
    {
      const uint4* gw = (const uint4*)&Wb[(size_t)sr * 256 + kcol];
      uint4 v0 = gw[0], v1 = gw[1];
      *(uint4*)&sW[sr][sh * 16] = v0;
      *(uint4*)&sW[sr][sh * 16 + 8] = v1;
      const uint4* gx = (const uint4*)&h1T[(size_t)(i0 + sr) * 256 + kcol];
      uint4 x0 = gx[0], x1 = gx[1];
      unsigned rr[8] = {x0.x, x0.y, x0.z, x0.w, x1.x, x1.y, x1.z, x1.w};
      unsigned ww[8];
#pragma unroll
      for (int e = 0; e < 8; ++e) {  // BN1+relu fused while staging
        int ch = kcol + 2 * e;
        float f0 = bf2f((unsigned short)(rr[e] & 0xFFFFu));
        float f1 = bf2f((unsigned short)(rr[e] >> 16));
        f0 = fmaxf(fmaf(sA1[ch], f0, sC1[ch]), 0.f);
        f1 = fmaxf(fmaf(sA1[ch + 1], f1, sC1[ch + 1]), 0.f);
        ww[e] = (unsigned)f2bf(f0) | ((unsigned)f2bf(f1) << 16);
      }
      uint4 y0 = {ww[0], ww[1], ww[2], ww[3]};
      uint4 y1 = {ww[4], ww[5], ww[6], ww[7]};
      *(uint4*)&sX[sr][sh * 16] = y0;
      *(uint4*)&sX[sr][sh * 16 + 8] = y1;
    }
    __syncthreads();
    bf16x8 a[4], b[4];
#pragma unroll
    for (int tm = 0; tm < 4; ++tm)
      a[tm] = *(const bf16x8*)&sW[wc + tm * 16 + l15][g * 8];
#pragma unroll
    for (int tn = 0; tn < 4; ++tn)
      b[tn] = *(const bf16x8*)&sX[wn + tn * 16 + l15][g * 8];
#pragma unroll
    for (int tm = 0; tm < 4; ++tm)
#pragma unroll
      for (int tn = 0; tn < 4; ++tn)
        acc[tm][tn] = __builtin_amdgcn_mfma_f32_16x16x32_bf16(a[tm], b[tn], acc[tm][tn], 0, 0, 0);
  }
#pragma unroll
  for (int tm = 0; tm < 4; ++tm)
#pragma unroll
    for (int tn = 0; tn < 4; ++tn) {
      int c = wc + tm * 16 + g * 4;
      int n = i0 + wn + tn * 16 + l15;
      f32x4 v = acc[tm][tn];
      ushort4 o;
      o.x = f2bf(v[0]); o.y = f2bf(v[1]); o.z = f2bf(v[2]); o.w = f2bf(v[3]);
      *(ushort4*)&o2[(size_t)n * 128 + c] = o;
    }
  // --- fused BN2 stats (fp32 acc) -> atomicAdd ---
  float s_[4][4], q_[4][4];
#pragma unroll
  for (int tm = 0; tm < 4; ++tm)
#pragma unroll
    for (int j = 0; j < 4; ++j) {
      float s = 0.f, q = 0.f;
#pragma unroll
      for (int tn = 0; tn < 4; ++tn) {
        float v = acc[tm][tn][j];
        s += v; q = fmaf(v, v, q);
      }
      s_[tm][j] = s; q_[tm][j] = q;
    }
#pragma unroll
  for (int mask = 1; mask < 16; mask <<= 1)
#pragma unroll
    for (int tm = 0; tm < 4; ++tm)
#pragma unroll
      for (int j = 0; j < 4; ++j) {
        s_[tm][j] += __shfl_xor(s_[tm][j], mask);
        q_[tm][j] += __shfl_xor(q_[tm][j], mask);
      }
  __syncthreads();
  float* red = (float*)&sW[0][0];  // [2][128][2]
  if (l15 == 0) {
#pragma unroll
    for (int tm = 0; tm < 4; ++tm)
#pragma unroll
      for (int j = 0; j < 4; ++j) {
        int cl = wc + tm * 16 + g * 4 + j;
        red[(wni * 128 + cl) * 2 + 0] = s_[tm][j];
        red[(wni * 128 + cl) * 2 + 1] = q_[tm][j];
      }
  }
  __syncthreads();
  {
    int cl = t >> 1, st = t & 1;
    float v = red[(0 * 128 + cl) * 2 + st] + red[(1 * 128 + cl) * 2 + st];
    atomicAdd(&stats2[(cl << 1) + st], v);
  }
}

// final: fold stats2 -> BN2 a/c, apply + relu, transpose o2 bf16 [i][128]
// -> d_out [B][128][16384] fp32.
__global__ __launch_bounds__(256) void final_k(const unsigned short* __restrict__ o2,
                                               const float* __restrict__ stats2,
                                               const float* __restrict__ g2,
                                               const float* __restrict__ be2,
                                               float* __restrict__ out) {
  __shared__ float tile[32][33];
  __shared__ float sA2[128], sC2[128];
  int b = blockIdx.z;
  int n0 = blockIdx.x * 32;
  int c0 = blockIdx.y * 32;
  int tx = threadIdx.x, ty = threadIdx.y;
  int tid = ty * 32 + tx;
  if (tid < 128) {  // fold BN2 (redundant per block; 128 ch, trivial)
    float s1v = stats2[tid * 2 + 0], s2v = stats2[tid * 2 + 1];
    float mean = s1v * (1.f / 65536.f);
    float var = s2v * (1.f / 65536.f) - mean * mean;  // biased, as torch BN
    float a = g2[tid] * rsqrtf(var + 1e-5f);
    sA2[tid] = a;
    sC2[tid] = be2[tid] - mean * a;
  }
  __syncthreads();
  float a = sA2[c0 + tx], cc = sC2[c0 + tx];
  for (int r = ty; r < 32; r += 8) {
    float v = bf2f(o2[(size_t)(b * 16384 + n0 + r) * 128 + c0 + tx]);
    tile[r][tx] = fmaxf(fmaf(a, v, cc), 0.f);
  }
  __syncthreads();
  for (int r = ty; r < 32; r += 8)
    out[((size_t)(b * 128 + c0 + r)) * 16384 + n0 + tx] = tile[tx][r];
}

extern "C" void kernel_launch(void* const* d_in, const int* in_sizes, int n_in,
                              void* d_out, int out_size, void* d_ws, size_t ws_size,
                              hipStream_t stream) {
  const float* xyz1 = (const float*)d_in[0];
  const float* xyz2 = (const float*)d_in[1];
  const float* p1   = (const float*)d_in[2];
  const float* p2   = (const float*)d_in[3];
  const int*   idx1 = (const int*)d_in[4];
  const int*   idx2 = (const int*)d_in[5];
  const float* w1   = (const float*)d_in[6];
  // d_in[7]=b1, d_in[11]=b2: exactly absorbed by BN mean subtraction
  const float* g1   = (const float*)d_in[8];
  const float* be1  = (const float*)d_in[9];
  const float* w2   = (const float*)d_in[10];
  const float* g2   = (const float*)d_in[12];
  const float* be2  = (const float*)d_in[13];
  float* out = (float*)d_out;

  char* ws = (char*)d_ws;
  // X 48MB | h1T 32MB (p2t bf16 8.4MB aliased: dead before gemm1 writes)
  // | o2 bf16 16MB (rec 12.6MB aliased: dead before gemm2 writes) | w1b w2b
  // | pack 262KB | stats 3KB  => ~98MB
  unsigned short* X    = (unsigned short*)(ws + 0x180000);      // 48MB
  unsigned short* h1T  = (unsigned short*)(ws + 0x3180000);     // 32MB
  unsigned short* p2t  = (unsigned short*)(ws + 0x3180000);     // alias h1T
  unsigned short* o2   = (unsigned short*)(ws + 0x5180000);     // 16MB
  float*          rec  = (float*)(ws + 0x5180000);              // alias o2
  unsigned short* w1b  = (unsigned short*)(ws + 0x7180000);
  unsigned short* w2b  = (unsigned short*)(ws + 0x71B0000);
  float4*         pack = (float4*)(ws + 0x71C0000);             // 262KB
  float*          stats = (float*)(ws + 0x7208000);             // 768 floats
  float*          stats1 = stats;                               // [256][2]
  float*          stats2 = stats + 512;                         // [128][2]

  hipLaunchKernelGGL(prep_k, dim3(12865), dim3(256), 0, stream,
                     p2, p1, w1, w2, xyz2, idx1, idx2, p2t, X, w1b, w2b, pack, stats);
  hipLaunchKernelGGL(knn_k, dim3(2048), dim3(256), 0, stream,
                     xyz1, xyz2, idx1, idx2, pack, rec);
  hipLaunchKernelGGL(interpm_k, dim3(512), dim3(256), 0, stream, rec, p2t, X);
  hipLaunchKernelGGL(gemm1_k, dim3(512, 2), dim3(256), 0, stream, X, w1b, h1T, stats1);
  hipLaunchKernelGGL(gemm2_k, dim3(512), dim3(256), 0, stream,
                     h1T, w2b, stats1, g1, be1, o2, stats2);
  hipLaunchKernelGGL(final_k, dim3(512, 4, 4), dim3(32, 8), 0, stream,
                     o2, stats2, g2, be2, out);
}

// Round 15
// 233.651 us; speedup vs baseline: 1.1956x; 1.0002x over previous
//
#include <hip/hip_runtime.h>
#include <hip/hip_bf16.h>

#define INF_F (__builtin_inff())

typedef __attribute__((ext_vector_type(8))) short bf16x8;
typedef __attribute__((ext_vector_type(4))) float f32x4;

__device__ __forceinline__ unsigned short f2bf(float f) {
  __hip_bfloat16 h = __float2bfloat16(f);
  return __builtin_bit_cast(unsigned short, h);
}
__device__ __forceinline__ float bf2f(unsigned short u) {
  return __uint_as_float((unsigned)u << 16);
}

// branchy sorted top-3 insert (scalar state only - R8 lesson: nothing
// address-taken). Strict < + ascending s = top_k lowest-index tie order.
#define TOP3_INS(d, sj, E0, E1, E2, J0, J1, J2)                      \
  {                                                                  \
    bool l0 = (d) < E0, l1 = (d) < E1;                               \
    E2 = l1 ? E1 : (d); J2 = l1 ? J1 : (sj);                         \
    E1 = l0 ? E0 : (l1 ? (d) : E1); J1 = l0 ? J0 : (l1 ? (sj) : J1); \
    E0 = l0 ? (d) : E0; J0 = l0 ? (sj) : J0;                         \
  }

// ---------------------------------------------------------------------------
// B=4, N=16384, S=4096, D1=128, D2=256, MLP=(256,128). M = B*N = 65536.
// X: [65536][384] bf16 ; h1T: [65536][256] bf16 ; o2: [65536][128] bf16.
// GEMMs: D[c][n] = W[c][k] * X[n][k] via mfma_f32_16x16x32_bf16.
// R15: prep's memory work (p2/p1 transposes, weight cvt) folded into knn
// block prologues - knn is VALU-bound at 2% HBM, prep is pure memory, so
// the ~77MB of prep traffic drains under knn's 97us compute for free.
// ---------------------------------------------------------------------------

// pack sources (knn's only dependency) + zero BN stats accumulators.
// pack: [B][4096] float4 {x,y,z,|p|^2 or 3e38 if batch-id mismatch}.
__global__ __launch_bounds__(256) void pack_k(const float* __restrict__ xyz2,
                                              const int* __restrict__ idx1,
                                              const int* __restrict__ idx2,
                                              float4* __restrict__ pack,
                                              float* __restrict__ stats) {
  int id = blockIdx.x;
  int t = threadIdx.x;
  if (id < 64) {
    int pid = id * 256 + t;
    int b = pid >> 12, s = pid & 4095;
    float x = xyz2[(b * 3 + 0) * 4096 + s];
    float y = xyz2[(b * 3 + 1) * 4096 + s];
    float z = xyz2[(b * 3 + 2) * 4096 + s];
    float w = fmaf(x, x, fmaf(y, y, z * z));
    int common = idx1[b * 16384];
    w = (idx2[b * 4096 + s] == common) ? w : 3e38f;  // invalid -> wgt 0
    pack[b * 4096 + s] = make_float4(x, y, z, w);
  } else {
    for (int i = t; i < 768; i += 256) stats[i] = 0.f;
  }
}

// 3-NN stage 1 + fused prep. 2048 blocks = 256 query-groups x 8 S-slices.
// Prologue (per block): 2 p2-transpose tiles + 4 p1-transpose tiles (+ 1
// weight chunk for bid<512) - issues ~37KB of memory work whose completion
// overlaps this block's knn compute. Then 1 query/thread scalar-pipe knn
// (R12 structure: occ 62%, VALUBusy 82%, VGPR 12->~28, LDS 0->4.2KB, both
// under the 32-waves/CU limits).
__global__ __launch_bounds__(256) void knnprep_k(const float* __restrict__ xyz1,
                                                 const float* __restrict__ xyz2,
                                                 const int* __restrict__ idx1,
                                                 const int* __restrict__ idx2,
                                                 const float4* __restrict__ pack,
                                                 const float* __restrict__ p2,
                                                 const float* __restrict__ p1,
                                                 const float* __restrict__ w1,
                                                 const float* __restrict__ w2,
                                                 unsigned short* __restrict__ p2t,
                                                 unsigned short* __restrict__ X,
                                                 unsigned short* __restrict__ w1b,
                                                 unsigned short* __restrict__ w2b,
                                                 float* __restrict__ rec) {
  __shared__ float tile[32][33];
  int bid = blockIdx.x;
  int t = threadIdx.x;
  int tx = t & 31, ty = t >> 5;
  // --- fused prep: weights (blocks 0..511, 1 elem/thread) ---
  if (bid < 512) {
    int id3 = bid * 256 + t;
    if (id3 < 98304) w1b[id3] = f2bf(w1[id3]);
    else w2b[id3 - 98304] = f2bf(w2[id3 - 98304]);
  }
  // --- fused prep: 2 p2-transpose tiles (4096 total) ---
#pragma unroll
  for (int q = 0; q < 2; ++q) {
    int id = bid * 2 + q;
    int s0 = (id & 127) * 32;
    int k0 = ((id >> 7) & 7) * 32;
    int b = id >> 10;
    const float* src = p2 + ((size_t)b * 256 + k0) * 4096 + s0;
    __syncthreads();
    for (int r = ty; r < 32; r += 8) tile[r][tx] = src[(size_t)r * 4096 + tx];
    __syncthreads();
    unsigned short* dst = p2t + ((size_t)b * 4096 + s0) * 256 + k0;
    for (int r = ty; r < 32; r += 8) dst[(size_t)r * 256 + tx] = f2bf(tile[tx][r]);
  }
  // --- fused prep: 4 p1-transpose tiles (8192 total) ---
#pragma unroll
  for (int q = 0; q < 4; ++q) {
    int id2 = bid * 4 + q;
    int n0 = (id2 & 511) * 32;
    int c0 = ((id2 >> 9) & 3) * 32;
    int b = id2 >> 11;
    const float* src = p1 + ((size_t)b * 128 + c0) * 16384 + n0;
    __syncthreads();
    for (int r = ty; r < 32; r += 8) tile[r][tx] = src[(size_t)r * 16384 + tx];
    __syncthreads();
    for (int r = ty; r < 32; r += 8)
      X[((size_t)(b * 16384 + n0 + r)) * 384 + c0 + tx] = f2bf(tile[tx][r]);
  }
  // --- knn ---
  int qg = bid >> 3, sl = bid & 7;
  int b = qg >> 6;               // 64 query-groups per batch
  int nloc = (qg & 63) << 8;     // 256 queries per group
  int n = nloc + t;
  int q0i = b * 16384 + n;
  int common = idx1[b * 16384];
  int sbase = sl << 9;           // 512-source slice
  const float4* ps = pack + b * 4096 + sbase;
  float px = xyz1[(b * 3 + 0) * 16384 + n];
  float py = xyz1[(b * 3 + 1) * 16384 + n];
  float pz = xyz1[(b * 3 + 2) * 16384 + n];
  int myid = idx1[q0i];
  float pn = fmaf(px, px, fmaf(py, py, pz * pz));
  float qx = -2.f * px, qy = -2.f * py, qz = -2.f * pz;
  float e0 = INF_F, e1 = INF_F, e2 = INF_F;
  int j0 = 0, j1 = 0, j2 = 0;
#pragma unroll 8
  for (int s = 0; s < 512; ++s) {
    float4 p = ps[s];  // uniform addr -> scalar load (s_load_dwordx4/x16)
    float d = fmaf(qx, p.x, fmaf(qy, p.y, fmaf(qz, p.z, pn))) + p.w;
    if (__builtin_expect(d < e2, 0)) {  // 64 states/wave: genuinely skippable
      int sj = sbase + s;
      TOP3_INS(d, sj, e0, e1, e2, j0, j1, j2);
    }
  }
  if (__builtin_expect(myid != common, 0)) {  // exact general-idx fallback
    e0 = INF_F; e1 = INF_F; e2 = INF_F; j0 = 0; j1 = 0; j2 = 0;
    for (int s = 0; s < 512; ++s) {
      int gs = sbase + s;
      float x = xyz2[(b * 3 + 0) * 4096 + gs];
      float y = xyz2[(b * 3 + 1) * 4096 + gs];
      float z = xyz2[(b * 3 + 2) * 4096 + gs];
      float w = fmaf(x, x, fmaf(y, y, z * z));
      float d = fmaf(qx, x, fmaf(qy, y, fmaf(qz, z, pn))) + w;
      d = (idx2[b * 4096 + gs] == myid) ? d : INF_F;
      if (d < e2) TOP3_INS(d, gs, e0, e1, e2, j0, j1, j2);
    }
  }
  // rec layout [slice][query]: lane-consecutive 24B records => coalesced
  float* r = &rec[((size_t)sl * 65536 + q0i) * 6];
  r[0] = e0; r[1] = e1; r[2] = e2;
  ((int*)r)[3] = j0; ((int*)r)[4] = j1; ((int*)r)[5] = j2;
}

// fused: merge 8 S-slice records (lex (d,idx), ascending slice order = exact
// top_k ties) + inverse-distance weights + gather-interpolate into X.
// 512 blocks x 256 thr; block = 128 queries.
__global__ __launch_bounds__(256) void interpm_k(const float* __restrict__ rec,
                                                 const unsigned short* __restrict__ p2t,
                                                 unsigned short* __restrict__ X) {
  __shared__ int sId[128][3];
  __shared__ float sWt[128][3];
  int i0 = blockIdx.x * 128;
  int b = i0 >> 14;
  int t = threadIdx.x;
  if (t < 128) {
    int i = i0 + t;
    float e0, e1, e2;
    int j0, j1, j2;
    {
      const float* r = &rec[(size_t)i * 6];
      e0 = r[0]; e1 = r[1]; e2 = r[2];
      j0 = ((const int*)r)[3]; j1 = ((const int*)r)[4]; j2 = ((const int*)r)[5];
    }
#pragma unroll
    for (int c = 1; c < 8; ++c) {
      const float* r = &rec[((size_t)c * 65536 + i) * 6];
      const int* ir = (const int*)r;
#pragma unroll
      for (int w = 0; w < 3; ++w) {
        float d = r[w];
        int sj = ir[3 + w];
        bool l0 = (d < e0) || (d == e0 && sj < j0);
        bool l1 = (d < e1) || (d == e1 && sj < j1);
        bool l2 = (d < e2) || (d == e2 && sj < j2);
        e2 = l1 ? e1 : (l2 ? d : e2);
        j2 = l1 ? j1 : (l2 ? sj : j2);
        e1 = l0 ? e0 : (l1 ? d : e1);
        j1 = l0 ? j0 : (l1 ? sj : j1);
        e0 = l0 ? d : e0;
        j0 = l0 ? sj : j0;
      }
    }
    float r0 = 1.f / (e0 + 1e-8f);
    float r1 = 1.f / (e1 + 1e-8f);
    float r2 = 1.f / (e2 + 1e-8f);
    float rs = r0 + r1 + r2;
    sWt[t][0] = (e0 > 1e8f) ? 0.f : r0 / rs;  // ref: where(d3>BIG,0)+nan_to_num
    sWt[t][1] = (e1 > 1e8f) ? 0.f : r1 / rs;
    sWt[t][2] = (e2 > 1e8f) ? 0.f : r2 / rs;
    sId[t][0] = j0; sId[t][1] = j1; sId[t][2] = j2;
  }
  __syncthreads();
  int k = t;
  const unsigned short* base = p2t + (size_t)b * 4096 * 256;
#pragma unroll 2
  for (int ii = 0; ii < 128; ++ii) {
    int id0 = sId[ii][0], id1 = sId[ii][1], id2 = sId[ii][2];
    float w0 = sWt[ii][0], w1v = sWt[ii][1], w2v = sWt[ii][2];
    float v = w0 * bf2f(base[id0 * 256 + k]);
    v = fmaf(w1v, bf2f(base[id1 * 256 + k]), v);
    v = fmaf(w2v, bf2f(base[id2 * 256 + k]), v);
    X[(size_t)(i0 + ii) * 384 + 128 + k] = f2bf(v);
  }
}

// GEMM1 (MFMA): h1T[n][c] = sum_k w1[c][k] X[n][k]. 128x128 tile, BK=32,
// K=384. grid (512, 2). Epilogue: per-block BN1 stats (sum,sumsq per
// channel over block's 128 n) from fp32 acc -> atomicAdd into stats1[256][2].
__global__ __launch_bounds__(256) void gemm1_k(const unsigned short* __restrict__ X,
                                               const unsigned short* __restrict__ Wb,
                                               unsigned short* __restrict__ h1T,
                                               float* __restrict__ stats1) {
  __shared__ unsigned short sW[128][40];
  __shared__ unsigned short sX[128][40];
  int t = threadIdx.x;
  int i0 = blockIdx.x * 128;
  int c0 = blockIdx.y * 128;
  int w = t >> 6, lane = t & 63;
  int wc = (w & 1) * 64, wni = w >> 1;
  int wn = wni * 64;
  int l15 = lane & 15, g = lane >> 4;
  f32x4 acc[4][4];
#pragma unroll
  for (int a = 0; a < 4; ++a)
#pragma unroll
    for (int bq = 0; bq < 4; ++bq) acc[a][bq] = (f32x4)0.f;
  int sr = t & 127, sh = t >> 7;
  for (int kc = 0; kc < 12; ++kc) {
    int k0 = kc * 32;
    __syncthreads();
    {
      const uint4* gw = (const uint4*)&Wb[(size_t)(c0 + sr) * 384 + k0 + sh * 16];
      uint4 v0 = gw[0], v1 = gw[1];
      *(uint4*)&sW[sr][sh * 16] = v0;
      *(uint4*)&sW[sr][sh * 16 + 8] = v1;
      const uint4* gx = (const uint4*)&X[(size_t)(i0 + sr) * 384 + k0 + sh * 16];
      uint4 x0 = gx[0], x1 = gx[1];
      *(uint4*)&sX[sr][sh * 16] = x0;
      *(uint4*)&sX[sr][sh * 16 + 8] = x1;
    }
    __syncthreads();
    bf16x8 a[4], b[4];
#pragma unroll
    for (int tm = 0; tm < 4; ++tm)
      a[tm] = *(const bf16x8*)&sW[wc + tm * 16 + l15][g * 8];
#pragma unroll
    for (int tn = 0; tn < 4; ++tn)
      b[tn] = *(const bf16x8*)&sX[wn + tn * 16 + l15][g * 8];
#pragma unroll
    for (int tm = 0; tm < 4; ++tm)
#pragma unroll
      for (int tn = 0; tn < 4; ++tn)
        acc[tm][tn] = __builtin_amdgcn_mfma_f32_16x16x32_bf16(a[tm], b[tn], acc[tm][tn], 0, 0, 0);
  }
#pragma unroll
  for (int tm = 0; tm < 4; ++tm)
#pragma unroll
    for (int tn = 0; tn < 4; ++tn) {
      int c = c0 + wc + tm * 16 + g * 4;
      int n = i0 + wn + tn * 16 + l15;
      f32x4 v = acc[tm][tn];
      ushort4 o;
      o.x = f2bf(v[0]); o.y = f2bf(v[1]); o.z = f2bf(v[2]); o.w = f2bf(v[3]);
      *(ushort4*)&h1T[(size_t)n * 256 + c] = o;
    }
  // --- fused BN1 stats (fp32 acc) -> atomicAdd ---
  float s_[4][4], q_[4][4];
#pragma unroll
  for (int tm = 0; tm < 4; ++tm)
#pragma unroll
    for (int j = 0; j < 4; ++j) {
      float s = 0.f, q = 0.f;
#pragma unroll
      for (int tn = 0; tn < 4; ++tn) {
        float v = acc[tm][tn][j];
        s += v; q = fmaf(v, v, q);
      }
      s_[tm][j] = s; q_[tm][j] = q;
    }
#pragma unroll
  for (int mask = 1; mask < 16; mask <<= 1)
#pragma unroll
    for (int tm = 0; tm < 4; ++tm)
#pragma unroll
      for (int j = 0; j < 4; ++j) {
        s_[tm][j] += __shfl_xor(s_[tm][j], mask);
        q_[tm][j] += __shfl_xor(q_[tm][j], mask);
      }
  __syncthreads();                 // LDS reuse: sW as float red[2][128][2]
  float* red = (float*)&sW[0][0];
  if (l15 == 0) {
#pragma unroll
    for (int tm = 0; tm < 4; ++tm)
#pragma unroll
      for (int j = 0; j < 4; ++j) {
        int cl = wc + tm * 16 + g * 4 + j;
        red[(wni * 128 + cl) * 2 + 0] = s_[tm][j];
        red[(wni * 128 + cl) * 2 + 1] = q_[tm][j];
      }
  }
  __syncthreads();
  {
    int cl = t >> 1, st = t & 1;
    float v = red[(0 * 128 + cl) * 2 + st] + red[(1 * 128 + cl) * 2 + st];
    atomicAdd(&stats1[((c0 + cl) << 1) + st], v);
  }
}

// GEMM2 (MFMA). Prologue: fold stats1 -> per-channel BN1 a/c in LDS.
// Staging: BN1+relu fused. Epilogue: bf16 o2 write + BN2 stats atomicAdd.
__global__ __launch_bounds__(256) void gemm2_k(const unsigned short* __restrict__ h1T,
                                               const unsigned short* __restrict__ Wb,
                                               const float* __restrict__ stats1,
                                               const float* __restrict__ g1,
                                               const float* __restrict__ be1,
                                               unsigned short* __restrict__ o2,
                                               float* __restrict__ stats2) {
  __shared__ unsigned short sW[128][40];
  __shared__ unsigned short sX[128][40];
  __shared__ float sA1[256], sC1[256];
  int t = threadIdx.x;
  int i0 = blockIdx.x * 128;
  int w = t >> 6, lane = t & 63;
  int wc = (w & 1) * 64, wni = w >> 1;
  int wn = wni * 64;
  int l15 = lane & 15, g = lane >> 4;
  {  // fold BN1 (redundant per block; 256 ch, trivial)
    float s1v = stats1[t * 2 + 0], s2v = stats1[t * 2 + 1];
    float mean = s1v * (1.f / 65536.f);
    float var = s2v * (1.f / 65536.f) - mean * mean;  // biased, as torch BN
    float a = g1[t] * rsqrtf(var + 1e-5f);
    sA1[t] = a;
    sC1[t] = be1[t] - mean * a;
  }
  f32x4 acc[4][4];
#pragma unroll
  for (int a = 0; a < 4; ++a)
#pragma unroll
    for (int bq = 0; bq < 4; ++bq) acc[a][bq] = (f32x4)0.f;
  int sr = t & 127, sh = t >> 7;
  for (int kc = 0; kc < 8; ++kc) {
    int k0 = kc * 32;
    int kcol = k0 + sh * 16;
    __syncthreads();  // also covers prologue->staging dependency at kc=0
    {
      const uint4* gw = (const uint4*)&Wb[(size_t)sr * 256 + kcol];
      uint4 v0 = gw[0], v1 = gw[1];
      *(uint4*)&sW[sr][sh * 16] = v0;
      *(uint4*)&sW[sr][sh * 16 + 8] = v1;
      const uint4* gx = (const uint4*)&h1T[(size_t)(i0 + sr) * 256 + kcol];
      uint4 x0 = gx[0], x1 = gx[1];
      unsigned rr[8] = {x0.x, x0.y, x0.z, x0.w, x1.x, x1.y, x1.z, x1.w};
      unsigned ww[8];
#pragma unroll
      for (int e = 0; e < 8; ++e) {  // BN1+relu fused while staging
        int ch = kcol + 2 * e;
        float f0 = bf2f((unsigned short)(rr[e] & 0xFFFFu));
        float f1 = bf2f((unsigned short)(rr[e] >> 16));
        f0 = fmaxf(fmaf(sA1[ch], f0, sC1[ch]), 0.f);
        f1 = fmaxf(fmaf(sA1[ch + 1], f1, sC1[ch + 1]), 0.f);
        ww[e] = (unsigned)f2bf(f0) | ((unsigned)f2bf(f1) << 16);
      }
      uint4 y0 = {ww[0], ww[1], ww[2], ww[3]};
      uint4 y1 = {ww[4], ww[5], ww[6], ww[7]};
      *(uint4*)&sX[sr][sh * 16] = y0;
      *(uint4*)&sX[sr][sh * 16 + 8] = y1;
    }
    __syncthreads();
    bf16x8 a[4], b[4];
#pragma unroll
    for (int tm = 0; tm < 4; ++tm)
      a[tm] = *(const bf16x8*)&sW[wc + tm * 16 + l15][g * 8];
#pragma unroll
    for (int tn = 0; tn < 4; ++tn)
      b[tn] = *(const bf16x8*)&sX[wn + tn * 16 + l15][g * 8];
#pragma unroll
    for (int tm = 0; tm < 4; ++tm)
#pragma unroll
      for (int tn = 0; tn < 4; ++tn)
        acc[tm][tn] = __builtin_amdgcn_mfma_f32_16x16x32_bf16(a[tm], b[tn], acc[tm][tn], 0, 0, 0);
  }
#pragma unroll
  for (int tm = 0; tm < 4; ++tm)
#pragma unroll
    for (int tn = 0; tn < 4; ++tn) {
      int c = wc + tm * 16 + g * 4;
      int n = i0 + wn + tn * 16 + l15;
      f32x4 v = acc[tm][tn];
      ushort4 o;
      o.x = f2bf(v[0]); o.y = f2bf(v[1]); o.z = f2bf(v[2]); o.w = f2bf(v[3]);
      *(ushort4*)&o2[(size_t)n * 128 + c] = o;
    }
  // --- fused BN2 stats (fp32 acc) -> atomicAdd ---
  float s_[4][4], q_[4][4];
#pragma unroll
  for (int tm = 0; tm < 4; ++tm)
#pragma unroll
    for (int j = 0; j < 4; ++j) {
      float s = 0.f, q = 0.f;
#pragma unroll
      for (int tn = 0; tn < 4; ++tn) {
        float v = acc[tm][tn][j];
        s += v; q = fmaf(v, v, q);
      }
      s_[tm][j] = s; q_[tm][j] = q;
    }
#pragma unroll
  for (int mask = 1; mask < 16; mask <<= 1)
#pragma unroll
    for (int tm = 0; tm < 4; ++tm)
#pragma unroll
      for (int j = 0; j < 4; ++j) {
        s_[tm][j] += __shfl_xor(s_[tm][j], mask);
        q_[tm][j] += __shfl_xor(q_[tm][j], mask);
      }
  __syncthreads();
  float* red = (float*)&sW[0][0];  // [2][128][2]
  if (l15 == 0) {
#pragma unroll
    for (int tm = 0; tm < 4; ++tm)
#pragma unroll
      for (int j = 0; j < 4; ++j) {
        int cl = wc + tm * 16 + g * 4 + j;
        red[(wni * 128 + cl) * 2 + 0] = s_[tm][j];
        red[(wni * 128 + cl) * 2 + 1] = q_[tm][j];
      }
  }
  __syncthreads();
  {
    int cl = t >> 1, st = t & 1;
    float v = red[(0 * 128 + cl) * 2 + st] + red[(1 * 128 + cl) * 2 + st];
    atomicAdd(&stats2[(cl << 1) + st], v);
  }
}

// final: fold stats2 -> BN2 a/c, apply + relu, transpose o2 bf16 [i][128]
// -> d_out [B][128][16384] fp32.
__global__ __launch_bounds__(256) void final_k(const unsigned short* __restrict__ o2,
                                               const float* __restrict__ stats2,
                                               const float* __restrict__ g2,
                                               const float* __restrict__ be2,
                                               float* __restrict__ out) {
  __shared__ float tile[32][33];
  __shared__ float sA2[128], sC2[128];
  int b = blockIdx.z;
  int n0 = blockIdx.x * 32;
  int c0 = blockIdx.y * 32;
  int tx = threadIdx.x, ty = threadIdx.y;
  int tid = ty * 32 + tx;
  if (tid < 128) {  // fold BN2 (redundant per block; 128 ch, trivial)
    float s1v = stats2[tid * 2 + 0], s2v = stats2[tid * 2 + 1];
    float mean = s1v * (1.f / 65536.f);
    float var = s2v * (1.f / 65536.f) - mean * mean;  // biased, as torch BN
    float a = g2[tid] * rsqrtf(var + 1e-5f);
    sA2[tid] = a;
    sC2[tid] = be2[tid] - mean * a;
  }
  __syncthreads();
  float a = sA2[c0 + tx], cc = sC2[c0 + tx];
  for (int r = ty; r < 32; r += 8) {
    float v = bf2f(o2[(size_t)(b * 16384 + n0 + r) * 128 + c0 + tx]);
    tile[r][tx] = fmaxf(fmaf(a, v, cc), 0.f);
  }
  __syncthreads();
  for (int r = ty; r < 32; r += 8)
    out[((size_t)(b * 128 + c0 + r)) * 16384 + n0 + tx] = tile[tx][r];
}

extern "C" void kernel_launch(void* const* d_in, const int* in_sizes, int n_in,
                              void* d_out, int out_size, void* d_ws, size_t ws_size,
                              hipStream_t stream) {
  const float* xyz1 = (const float*)d_in[0];
  const float* xyz2 = (const float*)d_in[1];
  const float* p1   = (const float*)d_in[2];
  const float* p2   = (const float*)d_in[3];
  const int*   idx1 = (const int*)d_in[4];
  const int*   idx2 = (const int*)d_in[5];
  const float* w1   = (const float*)d_in[6];
  // d_in[7]=b1, d_in[11]=b2: exactly absorbed by BN mean subtraction
  const float* g1   = (const float*)d_in[8];
  const float* be1  = (const float*)d_in[9];
  const float* w2   = (const float*)d_in[10];
  const float* g2   = (const float*)d_in[12];
  const float* be2  = (const float*)d_in[13];
  float* out = (float*)d_out;

  char* ws = (char*)d_ws;
  // X 48MB | h1T 32MB (p2t bf16 8.4MB aliased: dead before gemm1 writes)
  // | o2 bf16 16MB (rec 12.6MB aliased: dead before gemm2 writes) | w1b w2b
  // | pack 262KB | stats 3KB  => ~98MB
  unsigned short* X    = (unsigned short*)(ws + 0x180000);      // 48MB
  unsigned short* h1T  = (unsigned short*)(ws + 0x3180000);     // 32MB
  unsigned short* p2t  = (unsigned short*)(ws + 0x3180000);     // alias h1T
  unsigned short* o2   = (unsigned short*)(ws + 0x5180000);     // 16MB
  float*          rec  = (float*)(ws + 0x5180000);              // alias o2
  unsigned short* w1b  = (unsigned short*)(ws + 0x7180000);
  unsigned short* w2b  = (unsigned short*)(ws + 0x71B0000);
  float4*         pack = (float4*)(ws + 0x71C0000);             // 262KB
  float*          stats = (float*)(ws + 0x7208000);             // 768 floats
  float*          stats1 = stats;                               // [256][2]
  float*          stats2 = stats + 512;                         // [128][2]

  hipLaunchKernelGGL(pack_k, dim3(65), dim3(256), 0, stream,
                     xyz2, idx1, idx2, pack, stats);
  hipLaunchKernelGGL(knnprep_k, dim3(2048), dim3(256), 0, stream,
                     xyz1, xyz2, idx1, idx2, pack, p2, p1, w1, w2,
                     p2t, X, w1b, w2b, rec);
  hipLaunchKernelGGL(interpm_k, dim3(512), dim3(256), 0, stream, rec, p2t, X);
  hipLaunchKernelGGL(gemm1_k, dim3(512, 2), dim3(256), 0, stream, X, w1b, h1T, stats1);
  hipLaunchKernelGGL(gemm2_k, dim3(512), dim3(256), 0, stream,
                     h1T, w2b, stats1, g1, be1, o2, stats2);
  hipLaunchKernelGGL(final_k, dim3(512, 4, 4), dim3(32, 8), 0, stream,
                     o2, stats2, g2, be2, out);
}

// Round 16
// 230.281 us; speedup vs baseline: 1.2131x; 1.0146x over previous
//
#include <hip/hip_runtime.h>
#include <hip/hip_bf16.h>

#define INF_F (__builtin_inff())

typedef __attribute__((ext_vector_type(8))) short bf16x8;
typedef __attribute__((ext_vector_type(4))) float f32x4;

__device__ __forceinline__ unsigned short f2bf(float f) {
  __hip_bfloat16 h = __float2bfloat16(f);
  return __builtin_bit_cast(unsigned short, h);
}
__device__ __forceinline__ float bf2f(unsigned short u) {
  return __uint_as_float((unsigned)u << 16);
}

// branchy sorted top-3 insert (scalar state only - R8 lesson: nothing
// address-taken). Strict < + ascending s = top_k lowest-index tie order.
#define TOP3_INS(d, sj, E0, E1, E2, J0, J1, J2)                      \
  {                                                                  \
    bool l0 = (d) < E0, l1 = (d) < E1;                               \
    E2 = l1 ? E1 : (d); J2 = l1 ? J1 : (sj);                         \
    E1 = l0 ? E0 : (l1 ? (d) : E1); J1 = l0 ? J0 : (l1 ? (sj) : J1); \
    E0 = l0 ? (d) : E0; J0 = l0 ? (sj) : J0;                         \
  }

// ---------------------------------------------------------------------------
// B=4, N=16384, S=4096, D1=128, D2=256, MLP=(256,128). M = B*N = 65536.
// X: [65536][384] bf16 ; h1T: [65536][256] bf16 ; o2: [65536][128] bf16.
// GEMMs: D[c][n] = W[c][k] * X[n][k] via mfma_f32_16x16x32_bf16.
// R16: T14 async-split in knnprep - prep's global loads ISSUE before the
// knn loop (24 regs/thread in flight on vmcnt), knn loop runs on VALU +
// scalar loads (lgkmcnt - independent counter), transpose+store AFTER.
// HBM latency/bandwidth drains under the 97us compute instead of ahead
// of it (R15's fused prologue was serial: exactly +17us, zero overlap).
// ---------------------------------------------------------------------------

// pack sources (knn's only dependency) + zero BN stats accumulators.
// pack: [B][4096] float4 {x,y,z,|p|^2 or 3e38 if batch-id mismatch}.
__global__ __launch_bounds__(256) void pack_k(const float* __restrict__ xyz2,
                                              const int* __restrict__ idx1,
                                              const int* __restrict__ idx2,
                                              float4* __restrict__ pack,
                                              float* __restrict__ stats) {
  int id = blockIdx.x;
  int t = threadIdx.x;
  if (id < 64) {
    int pid = id * 256 + t;
    int b = pid >> 12, s = pid & 4095;
    float x = xyz2[(b * 3 + 0) * 4096 + s];
    float y = xyz2[(b * 3 + 1) * 4096 + s];
    float z = xyz2[(b * 3 + 2) * 4096 + s];
    float w = fmaf(x, x, fmaf(y, y, z * z));
    int common = idx1[b * 16384];
    w = (idx2[b * 4096 + s] == common) ? w : 3e38f;  // invalid -> wgt 0
    pack[b * 4096 + s] = make_float4(x, y, z, w);
  } else {
    for (int i = t; i < 768; i += 256) stats[i] = 0.f;
  }
}

// 3-NN stage 1 + T14-overlapped prep. 2048 blocks = 256 qgroups x 8 slices.
__global__ __launch_bounds__(256) void knnprep_k(const float* __restrict__ xyz1,
                                                 const float* __restrict__ xyz2,
                                                 const int* __restrict__ idx1,
                                                 const int* __restrict__ idx2,
                                                 const float4* __restrict__ pack,
                                                 const float* __restrict__ p2,
                                                 const float* __restrict__ p1,
                                                 const float* __restrict__ w1,
                                                 const float* __restrict__ w2,
                                                 unsigned short* __restrict__ p2t,
                                                 unsigned short* __restrict__ X,
                                                 unsigned short* __restrict__ w1b,
                                                 unsigned short* __restrict__ w2b,
                                                 float* __restrict__ rec) {
  __shared__ float tile[32][33];
  int bid = blockIdx.x;
  int t = threadIdx.x;
  int tx = t & 31, ty = t >> 5;
  // --- T14 stage A: ISSUE prep loads (no use -> no wait until stage C) ---
  float wv = 0.f;
  if (bid < 512) {
    int id3 = bid * 256 + t;
    wv = (id3 < 98304) ? w1[id3] : w2[id3 - 98304];
  }
  float t2r[2][4];  // 2 p2 tiles x 4 rows/thread
#pragma unroll
  for (int q = 0; q < 2; ++q) {
    int id = bid * 2 + q;
    int s0 = (id & 127) * 32;
    int k0 = ((id >> 7) & 7) * 32;
    int b = id >> 10;
    const float* src = p2 + ((size_t)b * 256 + k0) * 4096 + s0;
#pragma unroll
    for (int r4 = 0; r4 < 4; ++r4)
      t2r[q][r4] = src[(size_t)(ty + r4 * 8) * 4096 + tx];
  }
  float t1r[4][4];  // 4 p1 tiles x 4 rows/thread
#pragma unroll
  for (int q = 0; q < 4; ++q) {
    int id2 = bid * 4 + q;
    int n0 = (id2 & 511) * 32;
    int c0 = ((id2 >> 9) & 3) * 32;
    int b = id2 >> 11;
    const float* src = p1 + ((size_t)b * 128 + c0) * 16384 + n0;
#pragma unroll
    for (int r4 = 0; r4 < 4; ++r4)
      t1r[q][r4] = src[(size_t)(ty + r4 * 8) * 16384 + tx];
  }
  // --- T14 stage B: knn (VALU + s_load/lgkmcnt; vmem loads stay in flight) ---
  int qg = bid >> 3, sl = bid & 7;
  int b = qg >> 6;               // 64 query-groups per batch
  int nloc = (qg & 63) << 8;     // 256 queries per group
  int n = nloc + t;
  int q0i = b * 16384 + n;
  int common = idx1[b * 16384];
  int sbase = sl << 9;           // 512-source slice
  const float4* ps = pack + b * 4096 + sbase;
  float px = xyz1[(b * 3 + 0) * 16384 + n];
  float py = xyz1[(b * 3 + 1) * 16384 + n];
  float pz = xyz1[(b * 3 + 2) * 16384 + n];
  int myid = idx1[q0i];
  float pn = fmaf(px, px, fmaf(py, py, pz * pz));
  float qx = -2.f * px, qy = -2.f * py, qz = -2.f * pz;
  float e0 = INF_F, e1 = INF_F, e2 = INF_F;
  int j0 = 0, j1 = 0, j2 = 0;
#pragma unroll 8
  for (int s = 0; s < 512; ++s) {
    float4 p = ps[s];  // uniform addr -> scalar load (s_load_dwordx4/x16)
    float d = fmaf(qx, p.x, fmaf(qy, p.y, fmaf(qz, p.z, pn))) + p.w;
    if (__builtin_expect(d < e2, 0)) {  // 64 states/wave: genuinely skippable
      int sj = sbase + s;
      TOP3_INS(d, sj, e0, e1, e2, j0, j1, j2);
    }
  }
  if (__builtin_expect(myid != common, 0)) {  // exact general-idx fallback
    e0 = INF_F; e1 = INF_F; e2 = INF_F; j0 = 0; j1 = 0; j2 = 0;
    for (int s = 0; s < 512; ++s) {
      int gs = sbase + s;
      float x = xyz2[(b * 3 + 0) * 4096 + gs];
      float y = xyz2[(b * 3 + 1) * 4096 + gs];
      float z = xyz2[(b * 3 + 2) * 4096 + gs];
      float w = fmaf(x, x, fmaf(y, y, z * z));
      float d = fmaf(qx, x, fmaf(qy, y, fmaf(qz, z, pn))) + w;
      d = (idx2[b * 4096 + gs] == myid) ? d : INF_F;
      if (d < e2) TOP3_INS(d, gs, e0, e1, e2, j0, j1, j2);
    }
  }
  // rec layout [slice][query]: lane-consecutive 24B records => coalesced
  {
    float* r = &rec[((size_t)sl * 65536 + q0i) * 6];
    r[0] = e0; r[1] = e1; r[2] = e2;
    ((int*)r)[3] = j0; ((int*)r)[4] = j1; ((int*)r)[5] = j2;
  }
  // --- T14 stage C: write-late (vmcnt drains here; loads completed under B) ---
  if (bid < 512) {
    int id3 = bid * 256 + t;
    if (id3 < 98304) w1b[id3] = f2bf(wv);
    else w2b[id3 - 98304] = f2bf(wv);
  }
#pragma unroll
  for (int q = 0; q < 2; ++q) {
    int id = bid * 2 + q;
    int s0 = (id & 127) * 32;
    int k0 = ((id >> 7) & 7) * 32;
    int bb = id >> 10;
    __syncthreads();
#pragma unroll
    for (int r4 = 0; r4 < 4; ++r4) tile[ty + r4 * 8][tx] = t2r[q][r4];
    __syncthreads();
    unsigned short* dst = p2t + ((size_t)bb * 4096 + s0) * 256 + k0;
    for (int r = ty; r < 32; r += 8) dst[(size_t)r * 256 + tx] = f2bf(tile[tx][r]);
  }
#pragma unroll
  for (int q = 0; q < 4; ++q) {
    int id2 = bid * 4 + q;
    int n0 = (id2 & 511) * 32;
    int c0 = ((id2 >> 9) & 3) * 32;
    int bb = id2 >> 11;
    __syncthreads();
#pragma unroll
    for (int r4 = 0; r4 < 4; ++r4) tile[ty + r4 * 8][tx] = t1r[q][r4];
    __syncthreads();
    for (int r = ty; r < 32; r += 8)
      X[((size_t)(bb * 16384 + n0 + r)) * 384 + c0 + tx] = f2bf(tile[tx][r]);
  }
}

// fused: merge 8 S-slice records (lex (d,idx), ascending slice order = exact
// top_k ties) + inverse-distance weights + gather-interpolate into X.
// 512 blocks x 256 thr; block = 128 queries.
__global__ __launch_bounds__(256) void interpm_k(const float* __restrict__ rec,
                                                 const unsigned short* __restrict__ p2t,
                                                 unsigned short* __restrict__ X) {
  __shared__ int sId[128][3];
  __shared__ float sWt[128][3];
  int i0 = blockIdx.x * 128;
  int b = i0 >> 14;
  int t = threadIdx.x;
  if (t < 128) {
    int i = i0 + t;
    float e0, e1, e2;
    int j0, j1, j2;
    {
      const float* r = &rec[(size_t)i * 6];
      e0 = r[0]; e1 = r[1]; e2 = r[2];
      j0 = ((const int*)r)[3]; j1 = ((const int*)r)[4]; j2 = ((const int*)r)[5];
    }
#pragma unroll
    for (int c = 1; c < 8; ++c) {
      const float* r = &rec[((size_t)c * 65536 + i) * 6];
      const int* ir = (const int*)r;
#pragma unroll
      for (int w = 0; w < 3; ++w) {
        float d = r[w];
        int sj = ir[3 + w];
        bool l0 = (d < e0) || (d == e0 && sj < j0);
        bool l1 = (d < e1) || (d == e1 && sj < j1);
        bool l2 = (d < e2) || (d == e2 && sj < j2);
        e2 = l1 ? e1 : (l2 ? d : e2);
        j2 = l1 ? j1 : (l2 ? sj : j2);
        e1 = l0 ? e0 : (l1 ? d : e1);
        j1 = l0 ? j0 : (l1 ? sj : j1);
        e0 = l0 ? d : e0;
        j0 = l0 ? sj : j0;
      }
    }
    float r0 = 1.f / (e0 + 1e-8f);
    float r1 = 1.f / (e1 + 1e-8f);
    float r2 = 1.f / (e2 + 1e-8f);
    float rs = r0 + r1 + r2;
    sWt[t][0] = (e0 > 1e8f) ? 0.f : r0 / rs;  // ref: where(d3>BIG,0)+nan_to_num
    sWt[t][1] = (e1 > 1e8f) ? 0.f : r1 / rs;
    sWt[t][2] = (e2 > 1e8f) ? 0.f : r2 / rs;
    sId[t][0] = j0; sId[t][1] = j1; sId[t][2] = j2;
  }
  __syncthreads();
  int k = t;
  const unsigned short* base = p2t + (size_t)b * 4096 * 256;
#pragma unroll 2
  for (int ii = 0; ii < 128; ++ii) {
    int id0 = sId[ii][0], id1 = sId[ii][1], id2 = sId[ii][2];
    float w0 = sWt[ii][0], w1v = sWt[ii][1], w2v = sWt[ii][2];
    float v = w0 * bf2f(base[id0 * 256 + k]);
    v = fmaf(w1v, bf2f(base[id1 * 256 + k]), v);
    v = fmaf(w2v, bf2f(base[id2 * 256 + k]), v);
    X[(size_t)(i0 + ii) * 384 + 128 + k] = f2bf(v);
  }
}

// GEMM1 (MFMA): h1T[n][c] = sum_k w1[c][k] X[n][k]. 128x128 tile, BK=32,
// K=384. grid (512, 2). Epilogue: per-block BN1 stats (sum,sumsq per
// channel over block's 128 n) from fp32 acc -> atomicAdd into stats1[256][2].
__global__ __launch_bounds__(256) void gemm1_k(const unsigned short* __restrict__ X,
                                               const unsigned short* __restrict__ Wb,
                                               unsigned short* __restrict__ h1T,
                                               float* __restrict__ stats1) {
  __shared__ unsigned short sW[128][40];
  __shared__ unsigned short sX[128][40];
  int t = threadIdx.x;
  int i0 = blockIdx.x * 128;
  int c0 = blockIdx.y * 128;
  int w = t >> 6, lane = t & 63;
  int wc = (w & 1) * 64, wni = w >> 1;
  int wn = wni * 64;
  int l15 = lane & 15, g = lane >> 4;
  f32x4 acc[4][4];
#pragma unroll
  for (int a = 0; a < 4; ++a)
#pragma unroll
    for (int bq = 0; bq < 4; ++bq) acc[a][bq] = (f32x4)0.f;
  int sr = t & 127, sh = t >> 7;
  for (int kc = 0; kc < 12; ++kc) {
    int k0 = kc * 32;
    __syncthreads();
    {
      const uint4* gw = (const uint4*)&Wb[(size_t)(c0 + sr) * 384 + k0 + sh * 16];
      uint4 v0 = gw[0], v1 = gw[1];
      *(uint4*)&sW[sr][sh * 16] = v0;
      *(uint4*)&sW[sr][sh * 16 + 8] = v1;
      const uint4* gx = (const uint4*)&X[(size_t)(i0 + sr) * 384 + k0 + sh * 16];
      uint4 x0 = gx[0], x1 = gx[1];
      *(uint4*)&sX[sr][sh * 16] = x0;
      *(uint4*)&sX[sr][sh * 16 + 8] = x1;
    }
    __syncthreads();
    bf16x8 a[4], b[4];
#pragma unroll
    for (int tm = 0; tm < 4; ++tm)
      a[tm] = *(const bf16x8*)&sW[wc + tm * 16 + l15][g * 8];
#pragma unroll
    for (int tn = 0; tn < 4; ++tn)
      b[tn] = *(const bf16x8*)&sX[wn + tn * 16 + l15][g * 8];
#pragma unroll
    for (int tm = 0; tm < 4; ++tm)
#pragma unroll
      for (int tn = 0; tn < 4; ++tn)
        acc[tm][tn] = __builtin_amdgcn_mfma_f32_16x16x32_bf16(a[tm], b[tn], acc[tm][tn], 0, 0, 0);
  }
#pragma unroll
  for (int tm = 0; tm < 4; ++tm)
#pragma unroll
    for (int tn = 0; tn < 4; ++tn) {
      int c = c0 + wc + tm * 16 + g * 4;
      int n = i0 + wn + tn * 16 + l15;
      f32x4 v = acc[tm][tn];
      ushort4 o;
      o.x = f2bf(v[0]); o.y = f2bf(v[1]); o.z = f2bf(v[2]); o.w = f2bf(v[3]);
      *(ushort4*)&h1T[(size_t)n * 256 + c] = o;
    }
  // --- fused BN1 stats (fp32 acc) -> atomicAdd ---
  float s_[4][4], q_[4][4];
#pragma unroll
  for (int tm = 0; tm < 4; ++tm)
#pragma unroll
    for (int j = 0; j < 4; ++j) {
      float s = 0.f, q = 0.f;
#pragma unroll
      for (int tn = 0; tn < 4; ++tn) {
        float v = acc[tm][tn][j];
        s += v; q = fmaf(v, v, q);
      }
      s_[tm][j] = s; q_[tm][j] = q;
    }
#pragma unroll
  for (int mask = 1; mask < 16; mask <<= 1)
#pragma unroll
    for (int tm = 0; tm < 4; ++tm)
#pragma unroll
      for (int j = 0; j < 4; ++j) {
        s_[tm][j] += __shfl_xor(s_[tm][j], mask);
        q_[tm][j] += __shfl_xor(q_[tm][j], mask);
      }
  __syncthreads();                 // LDS reuse: sW as float red[2][128][2]
  float* red = (float*)&sW[0][0];
  if (l15 == 0) {
#pragma unroll
    for (int tm = 0; tm < 4; ++tm)
#pragma unroll
      for (int j = 0; j < 4; ++j) {
        int cl = wc + tm * 16 + g * 4 + j;
        red[(wni * 128 + cl) * 2 + 0] = s_[tm][j];
        red[(wni * 128 + cl) * 2 + 1] = q_[tm][j];
      }
  }
  __syncthreads();
  {
    int cl = t >> 1, st = t & 1;
    float v = red[(0 * 128 + cl) * 2 + st] + red[(1 * 128 + cl) * 2 + st];
    atomicAdd(&stats1[((c0 + cl) << 1) + st], v);
  }
}

// GEMM2 (MFMA). Prologue: fold stats1 -> per-channel BN1 a/c in LDS.
// Staging: BN1+relu fused. Epilogue: bf16 o2 write + BN2 stats atomicAdd.
__global__ __launch_bounds__(256) void gemm2_k(const unsigned short* __restrict__ h1T,
                                               const unsigned short* __restrict__ Wb,
                                               const float* __restrict__ stats1,
                                               const float* __restrict__ g1,
                                               const float* __restrict__ be1,
                                               unsigned short* __restrict__ o2,
                                               float* __restrict__ stats2) {
  __shared__ unsigned short sW[128][40];
  __shared__ unsigned short sX[128][40];
  __shared__ float sA1[256], sC1[256];
  int t = threadIdx.x;
  int i0 = blockIdx.x * 128;
  int w = t >> 6, lane = t & 63;
  int wc = (w & 1) * 64, wni = w >> 1;
  int wn = wni * 64;
  int l15 = lane & 15, g = lane >> 4;
  {  // fold BN1 (redundant per block; 256 ch, trivial)
    float s1v = stats1[t * 2 + 0], s2v = stats1[t * 2 + 1];
    float mean = s1v * (1.f / 65536.f);
    float var = s2v * (1.f / 65536.f) - mean * mean;  // biased, as torch BN
    float a = g1[t] * rsqrtf(var + 1e-5f);
    sA1[t] = a;
    sC1[t] = be1[t] - mean * a;
  }
  f32x4 acc[4][4];
#pragma unroll
  for (int a = 0; a < 4; ++a)
#pragma unroll
    for (int bq = 0; bq < 4; ++bq) acc[a][bq] = (f32x4)0.f;
  int sr = t & 127, sh = t >> 7;
  for (int kc = 0; kc < 8; ++kc) {
    int k0 = kc * 32;
    int kcol = k0 + sh * 16;
    __syncthreads();  // also covers prologue->staging dependency at kc=0
    {
      const uint4* gw = (const uint4*)&Wb[(size_t)sr * 256 + kcol];
      uint4 v0 = gw[0], v1 = gw[1];
      *(uint4*)&sW[sr][sh * 16] = v0;
      *(uint4*)&sW[sr][sh * 16 + 8] = v1;
      const uint4* gx = (const uint4*)&h1T[(size_t)(i0 + sr) * 256 + kcol];
      uint4 x0 = gx[0], x1 = gx[1];
      unsigned rr[8] = {x0.x, x0.y, x0.z, x0.w, x1.x, x1.y, x1.z, x1.w};
      unsigned ww[8];
#pragma unroll
      for (int e = 0; e < 8; ++e) {  // BN1+relu fused while staging
        int ch = kcol + 2 * e;
        float f0 = bf2f((unsigned short)(rr[e] & 0xFFFFu));
        float f1 = bf2f((unsigned short)(rr[e] >> 16));
        f0 = fmaxf(fmaf(sA1[ch], f0, sC1[ch]), 0.f);
        f1 = fmaxf(fmaf(sA1[ch + 1], f1, sC1[ch + 1]), 0.f);
        ww[e] = (unsigned)f2bf(f0) | ((unsigned)f2bf(f1) << 16);
      }
      uint4 y0 = {ww[0], ww[1], ww[2], ww[3]};
      uint4 y1 = {ww[4], ww[5], ww[6], ww[7]};
      *(uint4*)&sX[sr][sh * 16] = y0;
      *(uint4*)&sX[sr][sh * 16 + 8] = y1;
    }
    __syncthreads();
    bf16x8 a[4], b[4];
#pragma unroll
    for (int tm = 0; tm < 4; ++tm)
      a[tm] = *(const bf16x8*)&sW[wc + tm * 16 + l15][g * 8];
#pragma unroll
    for (int tn = 0; tn < 4; ++tn)
      b[tn] = *(const bf16x8*)&sX[wn + tn * 16 + l15][g * 8];
#pragma unroll
    for (int tm = 0; tm < 4; ++tm)
#pragma unroll
      for (int tn = 0; tn < 4; ++tn)
        acc[tm][tn] = __builtin_amdgcn_mfma_f32_16x16x32_bf16(a[tm], b[tn], acc[tm][tn], 0, 0, 0);
  }
#pragma unroll
  for (int tm = 0; tm < 4; ++tm)
#pragma unroll
    for (int tn = 0; tn < 4; ++tn) {
      int c = wc + tm * 16 + g * 4;
      int n = i0 + wn + tn * 16 + l15;
      f32x4 v = acc[tm][tn];
      ushort4 o;
      o.x = f2bf(v[0]); o.y = f2bf(v[1]); o.z = f2bf(v[2]); o.w = f2bf(v[3]);
      *(ushort4*)&o2[(size_t)n * 128 + c] = o;
    }
  // --- fused BN2 stats (fp32 acc) -> atomicAdd ---
  float s_[4][4], q_[4][4];
#pragma unroll
  for (int tm = 0; tm < 4; ++tm)
#pragma unroll
    for (int j = 0; j < 4; ++j) {
      float s = 0.f, q = 0.f;
#pragma unroll
      for (int tn = 0; tn < 4; ++tn) {
        float v = acc[tm][tn][j];
        s += v; q = fmaf(v, v, q);
      }
      s_[tm][j] = s; q_[tm][j] = q;
    }
#pragma unroll
  for (int mask = 1; mask < 16; mask <<= 1)
#pragma unroll
    for (int tm = 0; tm < 4; ++tm)
#pragma unroll
      for (int j = 0; j < 4; ++j) {
        s_[tm][j] += __shfl_xor(s_[tm][j], mask);
        q_[tm][j] += __shfl_xor(q_[tm][j], mask);
      }
  __syncthreads();
  float* red = (float*)&sW[0][0];  // [2][128][2]
  if (l15 == 0) {
#pragma unroll
    for (int tm = 0; tm < 4; ++tm)
#pragma unroll
      for (int j = 0; j < 4; ++j) {
        int cl = wc + tm * 16 + g * 4 + j;
        red[(wni * 128 + cl) * 2 + 0] = s_[tm][j];
        red[(wni * 128 + cl) * 2 + 1] = q_[tm][j];
      }
  }
  __syncthreads();
  {
    int cl = t >> 1, st = t & 1;
    float v = red[(0 * 128 + cl) * 2 + st] + red[(1 * 128 + cl) * 2 + st];
    atomicAdd(&stats2[(cl << 1) + st], v);
  }
}

// final: fold stats2 -> BN2 a/c, apply + relu, transpose o2 bf16 [i][128]
// -> d_out [B][128][16384] fp32.
__global__ __launch_bounds__(256) void final_k(const unsigned short* __restrict__ o2,
                                               const float* __restrict__ stats2,
                                               const float* __restrict__ g2,
                                               const float* __restrict__ be2,
                                               float* __restrict__ out) {
  __shared__ float tile[32][33];
  __shared__ float sA2[128], sC2[128];
  int b = blockIdx.z;
  int n0 = blockIdx.x * 32;
  int c0 = blockIdx.y * 32;
  int tx = threadIdx.x, ty = threadIdx.y;
  int tid = ty * 32 + tx;
  if (tid < 128) {  // fold BN2 (redundant per block; 128 ch, trivial)
    float s1v = stats2[tid * 2 + 0], s2v = stats2[tid * 2 + 1];
    float mean = s1v * (1.f / 65536.f);
    float var = s2v * (1.f / 65536.f) - mean * mean;  // biased, as torch BN
    float a = g2[tid] * rsqrtf(var + 1e-5f);
    sA2[tid] = a;
    sC2[tid] = be2[tid] - mean * a;
  }
  __syncthreads();
  float a = sA2[c0 + tx], cc = sC2[c0 + tx];
  for (int r = ty; r < 32; r += 8) {
    float v = bf2f(o2[(size_t)(b * 16384 + n0 + r) * 128 + c0 + tx]);
    tile[r][tx] = fmaxf(fmaf(a, v, cc), 0.f);
  }
  __syncthreads();
  for (int r = ty; r < 32; r += 8)
    out[((size_t)(b * 128 + c0 + r)) * 16384 + n0 + tx] = tile[tx][r];
}

extern "C" void kernel_launch(void* const* d_in, const int* in_sizes, int n_in,
                              void* d_out, int out_size, void* d_ws, size_t ws_size,
                              hipStream_t stream) {
  const float* xyz1 = (const float*)d_in[0];
  const float* xyz2 = (const float*)d_in[1];
  const float* p1   = (const float*)d_in[2];
  const float* p2   = (const float*)d_in[3];
  const int*   idx1 = (const int*)d_in[4];
  const int*   idx2 = (const int*)d_in[5];
  const float* w1   = (const float*)d_in[6];
  // d_in[7]=b1, d_in[11]=b2: exactly absorbed by BN mean subtraction
  const float* g1   = (const float*)d_in[8];
  const float* be1  = (const float*)d_in[9];
  const float* w2   = (const float*)d_in[10];
  const float* g2   = (const float*)d_in[12];
  const float* be2  = (const float*)d_in[13];
  float* out = (float*)d_out;

  char* ws = (char*)d_ws;
  // X 48MB | h1T 32MB (p2t bf16 8.4MB aliased: dead before gemm1 writes)
  // | o2 bf16 16MB (rec 12.6MB aliased: dead before gemm2 writes) | w1b w2b
  // | pack 262KB | stats 3KB  => ~98MB
  unsigned short* X    = (unsigned short*)(ws + 0x180000);      // 48MB
  unsigned short* h1T  = (unsigned short*)(ws + 0x3180000);     // 32MB
  unsigned short* p2t  = (unsigned short*)(ws + 0x3180000);     // alias h1T
  unsigned short* o2   = (unsigned short*)(ws + 0x5180000);     // 16MB
  float*          rec  = (float*)(ws + 0x5180000);              // alias o2
  unsigned short* w1b  = (unsigned short*)(ws + 0x7180000);
  unsigned short* w2b  = (unsigned short*)(ws + 0x71B0000);
  float4*         pack = (float4*)(ws + 0x71C0000);             // 262KB
  float*          stats = (float*)(ws + 0x7208000);             // 768 floats
  float*          stats1 = stats;                               // [256][2]
  float*          stats2 = stats + 512;                         // [128][2]

  hipLaunchKernelGGL(pack_k, dim3(65), dim3(256), 0, stream,
                     xyz2, idx1, idx2, pack, stats);
  hipLaunchKernelGGL(knnprep_k, dim3(2048), dim3(256), 0, stream,
                     xyz1, xyz2, idx1, idx2, pack, p2, p1, w1, w2,
                     p2t, X, w1b, w2b, rec);
  hipLaunchKernelGGL(interpm_k, dim3(512), dim3(256), 0, stream, rec, p2t, X);
  hipLaunchKernelGGL(gemm1_k, dim3(512, 2), dim3(256), 0, stream, X, w1b, h1T, stats1);
  hipLaunchKernelGGL(gemm2_k, dim3(512), dim3(256), 0, stream,
                     h1T, w2b, stats1, g1, be1, o2, stats2);
  hipLaunchKernelGGL(final_k, dim3(512, 4, 4), dim3(32, 8), 0, stream,
                     o2, stats2, g2, be2, out);
}